// Round 10
// baseline (213.739 us; speedup 1.0000x reference)
//
#include <hip/hip_runtime.h>
#include <hip/hip_bf16.h>

#define LRELU(x) ((x) > 0.f ? (x) : 0.2f * (x))
#define SCAN_TILE 1024
#define BSH 8          // bucket = 256 consecutive dst nodes (requires N < 131072)
#define EPB 4096       // edges per block in bucket phases

// ---------------- Bucketed CSR build ----------------
// Edge packing: bits [0,17) = src, bits [17,25) = dst & 255; bucket implicit in slab.

__global__ void bucket_hist_kernel(const int* __restrict__ dst, int* __restrict__ bhist,
                                   int E, int NB) {
    __shared__ int cnt[256];
    int t = threadIdx.x;
    cnt[t] = 0;
    __syncthreads();
    int e0 = blockIdx.x * EPB + t;
#pragma unroll
    for (int i = 0; i < EPB / 256; ++i) {
        int e = e0 + i * 256;
        if (e < E) atomicAdd(&cnt[dst[e] >> BSH], 1);
    }
    __syncthreads();
    if (t < NB && cnt[t]) atomicAdd(&bhist[t], cnt[t]);
}

__global__ void bucket_scan_kernel(const int* __restrict__ bhist, int* __restrict__ boff,
                                   int* __restrict__ bcur, int NB) {
    int t = threadIdx.x;
    int v = (t < NB) ? bhist[t] : 0;
    int lane = t & 63, wid = t >> 6;
    int x = v;
#pragma unroll
    for (int off = 1; off < 64; off <<= 1) {
        int y = __shfl_up(x, off, 64);
        if (lane >= off) x += y;
    }
    __shared__ int sw[4], sw2[4];
    if (lane == 63) sw[wid] = x;
    __syncthreads();
    if (t == 0) { int a = 0; for (int w = 0; w < 4; ++w) { sw2[w] = a; a += sw[w]; } }
    __syncthreads();
    int excl = x - v + sw2[wid];
    if (t < NB) { boff[t] = excl; bcur[t] = excl; }
    if (t == NB - 1) boff[NB] = excl + v;   // == E
}

__global__ void bucket_scatter_kernel(const int* __restrict__ src, const int* __restrict__ dst,
                                      int* __restrict__ bcur, unsigned* __restrict__ ebuf, int E) {
    __shared__ int cnt[256];
    __shared__ int base[256];
    int t = threadIdx.x;
    cnt[t] = 0;
    __syncthreads();
    unsigned pk[EPB / 256];
    int bb[EPB / 256];
    int e0 = blockIdx.x * EPB + t;
#pragma unroll
    for (int i = 0; i < EPB / 256; ++i) {
        int e = e0 + i * 256;
        int b = -1; unsigned p = 0;
        if (e < E) {
            int s = src[e], d = dst[e];
            b = d >> BSH;
            p = (unsigned)s | ((unsigned)(d & ((1 << BSH) - 1)) << 17);
            atomicAdd(&cnt[b], 1);
        }
        bb[i] = b; pk[i] = p;
    }
    __syncthreads();
    if (cnt[t]) base[t] = atomicAdd(&bcur[t], cnt[t]);
    __syncthreads();
    cnt[t] = 0;
    __syncthreads();
#pragma unroll
    for (int i = 0; i < EPB / 256; ++i) {
        if (bb[i] >= 0) {
            int pos = base[bb[i]] + atomicAdd(&cnt[bb[i]], 1);
            ebuf[pos] = pk[i];
        }
    }
}

__global__ void deg_count_kernel(const unsigned* __restrict__ ebuf, const int* __restrict__ boff,
                                 int* __restrict__ deg, int n) {
    __shared__ int cnt[256];
    int t = threadIdx.x, b = blockIdx.x;
    cnt[t] = 0;
    __syncthreads();
    int beg = boff[b], end = boff[b + 1];
    for (int j = beg + t; j < end; j += 256)
        atomicAdd(&cnt[(ebuf[j] >> 17) & 255], 1);
    __syncthreads();
    int node = (b << BSH) + t;
    if (node < n) deg[node] = cnt[t];
}

__global__ void blocksum_kernel(const int* __restrict__ deg, int* __restrict__ bsum, int n) {
    int t = threadIdx.x;
    int i0 = blockIdx.x * SCAN_TILE + t * 4;
    int v = 0;
    if (i0 + 3 < n) {
        int4 q = *reinterpret_cast<const int4*>(deg + i0);
        v = q.x + q.y + q.z + q.w;
    } else {
#pragma unroll
        for (int k = 0; k < 4; ++k) if (i0 + k < n) v += deg[i0 + k];
    }
#pragma unroll
    for (int off = 32; off; off >>= 1) v += __shfl_xor(v, off, 64);
    __shared__ int sw[4];
    int lane = t & 63, wid = t >> 6;
    if (lane == 0) sw[wid] = v;
    __syncthreads();
    if (t == 0) bsum[blockIdx.x] = sw[0] + sw[1] + sw[2] + sw[3];
}

__global__ void scan_bsum_kernel(const int* __restrict__ bsum, int* __restrict__ boff,
                                 int* __restrict__ total_out, int nb) {
    int t = threadIdx.x;  // 1024 threads
    int v = (t < nb) ? bsum[t] : 0;
    int lane = t & 63, wid = t >> 6;
    int x = v;
#pragma unroll
    for (int off = 1; off < 64; off <<= 1) {
        int y = __shfl_up(x, off, 64);
        if (lane >= off) x += y;
    }
    __shared__ int sw[16], sw2[16];
    if (lane == 63) sw[wid] = x;
    __syncthreads();
    if (t == 0) {
        int a = 0;
#pragma unroll
        for (int w = 0; w < 16; ++w) { sw2[w] = a; a += sw[w]; }
    }
    __syncthreads();
    int incl = x + sw2[wid];
    if (t < nb) boff[t] = incl - v;
    if (t == nb - 1) *total_out = incl;
}

__global__ void scan_final_kernel(const int* __restrict__ deg, const int* __restrict__ boff,
                                  int* __restrict__ rowstart, int n) {
    int t = threadIdx.x;
    int i0 = blockIdx.x * SCAN_TILE + t * 4;
    int v0 = 0, v1 = 0, v2 = 0, v3 = 0;
    if (i0 + 3 < n) {
        int4 q = *reinterpret_cast<const int4*>(deg + i0);
        v0 = q.x; v1 = q.y; v2 = q.z; v3 = q.w;
    } else {
        if (i0     < n) v0 = deg[i0];
        if (i0 + 1 < n) v1 = deg[i0 + 1];
        if (i0 + 2 < n) v2 = deg[i0 + 2];
        if (i0 + 3 < n) v3 = deg[i0 + 3];
    }
    int tsum = v0 + v1 + v2 + v3;
    int lane = t & 63, wid = t >> 6;
    int x = tsum;
#pragma unroll
    for (int off = 1; off < 64; off <<= 1) {
        int y = __shfl_up(x, off, 64);
        if (lane >= off) x += y;
    }
    __shared__ int sw[4], sw2[4];
    if (lane == 63) sw[wid] = x;
    __syncthreads();
    if (t == 0) {
        int a = 0;
#pragma unroll
        for (int w = 0; w < 4; ++w) { sw2[w] = a; a += sw[w]; }
    }
    __syncthreads();
    int excl = x - tsum + sw2[wid] + boff[blockIdx.x];
    int e0 = excl, e1 = e0 + v0, e2 = e1 + v1, e3 = e2 + v2;
    if (i0     < n) rowstart[i0]     = e0;
    if (i0 + 1 < n) rowstart[i0 + 1] = e1;
    if (i0 + 2 < n) rowstart[i0 + 2] = e2;
    if (i0 + 3 < n) rowstart[i0 + 3] = e3;
}

// Phase F: per-bucket final scatter -> colv + dstv (writes confined to bucket region).
__global__ void final_scatter_kernel(const unsigned* __restrict__ ebuf, const int* __restrict__ boff,
                                     const int* __restrict__ rowstart, int* __restrict__ colv,
                                     int* __restrict__ dstv, int n) {
    __shared__ int cur[256];
    int t = threadIdx.x, b = blockIdx.x;
    int node = (b << BSH) + t;
    if (node < n) cur[t] = rowstart[node];
    __syncthreads();
    int beg = boff[b], end = boff[b + 1];
    for (int j = beg + t; j < end; j += 256) {
        unsigned p = ebuf[j];
        int dlow = (p >> 17) & 255;
        int s = (int)(p & 0x1FFFF);
        int pos = atomicAdd(&cur[dlow], 1);
        colv[pos] = s;
        dstv[pos] = (b << BSH) + dlow;
    }
}

// ---------------- Projection: h = x @ W (+ fused h.a_src / h.a_dst reductions) ----------------

template <int K>
__global__ __launch_bounds__(256, 3) void proj_kernel(
        const float* __restrict__ x, const float* __restrict__ W,
        const float* __restrict__ a_src, const float* __restrict__ a_dst,
        float* __restrict__ h, float* __restrict__ as_out,
        float* __restrict__ ad_out, int n) {
    __shared__ float Wt[64 * (K + 1)];   // [col][k], stride K+1
    __shared__ float xsh[16 * K];        // 16-row chunk

    for (int i = threadIdx.x; i < K * 64; i += 256) {
        int k = i >> 6, c = i & 63;
        Wt[c * (K + 1) + k] = W[i];
    }

    int lane = threadIdx.x & 63, wid = threadIdx.x >> 6;
    float as_l = a_src[lane], ad_l = a_dst[lane];
    const float4* x4 = reinterpret_cast<const float4*>(x);
    float4* xsh4 = reinterpret_cast<float4*>(xsh);
    const int K4 = K / 4;
    int nchunk = (n + 15) >> 4;

    for (int ci = blockIdx.x; ci < nchunk; ci += gridDim.x) {
        int base = ci * 16;
        __syncthreads();
        for (int j = threadIdx.x; j < 16 * K4; j += 256) {
            int row = j / K4;
            int r = base + row;
            float4 v = make_float4(0.f, 0.f, 0.f, 0.f);
            if (r < n) v = x4[(size_t)r * K4 + (j - row * K4)];
            xsh4[j] = v;
        }
        __syncthreads();

        int r0 = base + wid * 4;
        float acc0 = 0.f, acc1 = 0.f, acc2 = 0.f, acc3 = 0.f;
        const float* wl = Wt + lane * (K + 1);
#pragma unroll 4
        for (int k4 = 0; k4 < K4; ++k4) {
            float4 va = xsh4[(wid * 4 + 0) * K4 + k4];
            float4 vb = xsh4[(wid * 4 + 1) * K4 + k4];
            float4 vc = xsh4[(wid * 4 + 2) * K4 + k4];
            float4 vd = xsh4[(wid * 4 + 3) * K4 + k4];
            float w0 = wl[k4 * 4 + 0];
            float w1 = wl[k4 * 4 + 1];
            float w2 = wl[k4 * 4 + 2];
            float w3 = wl[k4 * 4 + 3];
            acc0 = fmaf(va.x, w0, acc0); acc0 = fmaf(va.y, w1, acc0);
            acc0 = fmaf(va.z, w2, acc0); acc0 = fmaf(va.w, w3, acc0);
            acc1 = fmaf(vb.x, w0, acc1); acc1 = fmaf(vb.y, w1, acc1);
            acc1 = fmaf(vb.z, w2, acc1); acc1 = fmaf(vb.w, w3, acc1);
            acc2 = fmaf(vc.x, w0, acc2); acc2 = fmaf(vc.y, w1, acc2);
            acc2 = fmaf(vc.z, w2, acc2); acc2 = fmaf(vc.w, w3, acc2);
            acc3 = fmaf(vd.x, w0, acc3); acc3 = fmaf(vd.y, w1, acc3);
            acc3 = fmaf(vd.z, w2, acc3); acc3 = fmaf(vd.w, w3, acc3);
        }
        if (r0 + 0 < n) h[(size_t)(r0 + 0) * 64 + lane] = acc0;
        if (r0 + 1 < n) h[(size_t)(r0 + 1) * 64 + lane] = acc1;
        if (r0 + 2 < n) h[(size_t)(r0 + 2) * 64 + lane] = acc2;
        if (r0 + 3 < n) h[(size_t)(r0 + 3) * 64 + lane] = acc3;
        float s0 = acc0 * as_l, d0 = acc0 * ad_l;
        float s1 = acc1 * as_l, d1 = acc1 * ad_l;
        float s2 = acc2 * as_l, d2 = acc2 * ad_l;
        float s3 = acc3 * as_l, d3 = acc3 * ad_l;
#pragma unroll
        for (int off = 32; off; off >>= 1) {
            s0 += __shfl_xor(s0, off, 64); d0 += __shfl_xor(d0, off, 64);
            s1 += __shfl_xor(s1, off, 64); d1 += __shfl_xor(d1, off, 64);
            s2 += __shfl_xor(s2, off, 64); d2 += __shfl_xor(d2, off, 64);
            s3 += __shfl_xor(s3, off, 64); d3 += __shfl_xor(d3, off, 64);
        }
        if (lane == 0) {
            if (r0 + 0 < n) { as_out[r0 + 0] = s0; ad_out[r0 + 0] = d0; }
            if (r0 + 1 < n) { as_out[r0 + 1] = s1; ad_out[r0 + 1] = d1; }
            if (r0 + 2 < n) { as_out[r0 + 2] = s2; ad_out[r0 + 2] = d2; }
            if (r0 + 3 < n) { as_out[r0 + 3] = s3; ad_out[r0 + 3] = d3; }
        }
    }
}

// ---------------- Edge weights: ew[e] = exp(LRELU(as[src] + ad[dst])) ----------------
// Edge-parallel: gathers fully TLP-hidden, coalesced ew write. Removes exp + as-gather
// from agg's per-node serial loop.

__global__ void edge_weight_kernel(const int* __restrict__ colv, const int* __restrict__ dstv,
                                   const float* __restrict__ as_in, const float* __restrict__ ad_in,
                                   float* __restrict__ ew, int E) {
    int e = blockIdx.x * 256 + threadIdx.x;
    if (e < E) {
        float v = as_in[colv[e]] + ad_in[dstv[e]];
        ew[e] = __expf(LRELU(v));
    }
}

// ---------------- Aggregation: weighted gather-sum with precomputed weights ----------------
// One wave per node, lane = feature. Loop body: aligned int4/float4 uniform loads of
// colv/ew + 8 independent h-row gathers in flight.

template <bool ELU>
__global__ void agg_kernel(const float* __restrict__ h, const float* __restrict__ ew,
                           const int* __restrict__ colv,
                           const float* __restrict__ as_in, const float* __restrict__ ad_in,
                           const int* __restrict__ rowstart, const float* __restrict__ bias,
                           float* __restrict__ out, int n) {
    int node = blockIdx.x * 4 + (threadIdx.x >> 6);
    int lane = threadIdx.x & 63;
    if (node >= n) return;

    int beg = rowstart[node], end = rowstart[node + 1];

    // self-loop
    float ex = __expf(LRELU(as_in[node] + ad_in[node]));
    float denom = ex;
    float acc = h[(size_t)node * 64 + lane] * ex;

    int i = beg;
    int aligned = (beg + 3) & ~3;
    if (aligned > end) aligned = end;
    for (; i < aligned; ++i) {
        float w = ew[i];
        denom += w;
        acc = fmaf(h[(size_t)colv[i] * 64 + lane], w, acc);
    }
    for (; i + 7 < end; i += 8) {
        int4   c0 = *reinterpret_cast<const int4*>(colv + i);
        int4   c1 = *reinterpret_cast<const int4*>(colv + i + 4);
        float4 w0 = *reinterpret_cast<const float4*>(ew + i);
        float4 w1 = *reinterpret_cast<const float4*>(ew + i + 4);
        float h0 = h[(size_t)c0.x * 64 + lane];
        float h1 = h[(size_t)c0.y * 64 + lane];
        float h2 = h[(size_t)c0.z * 64 + lane];
        float h3 = h[(size_t)c0.w * 64 + lane];
        float h4 = h[(size_t)c1.x * 64 + lane];
        float h5 = h[(size_t)c1.y * 64 + lane];
        float h6 = h[(size_t)c1.z * 64 + lane];
        float h7 = h[(size_t)c1.w * 64 + lane];
        denom += ((w0.x + w0.y) + (w0.z + w0.w)) + ((w1.x + w1.y) + (w1.z + w1.w));
        acc = fmaf(h0, w0.x, acc);
        acc = fmaf(h1, w0.y, acc);
        acc = fmaf(h2, w0.z, acc);
        acc = fmaf(h3, w0.w, acc);
        acc = fmaf(h4, w1.x, acc);
        acc = fmaf(h5, w1.y, acc);
        acc = fmaf(h6, w1.z, acc);
        acc = fmaf(h7, w1.w, acc);
    }
    for (; i + 3 < end; i += 4) {
        int4   c0 = *reinterpret_cast<const int4*>(colv + i);
        float4 w0 = *reinterpret_cast<const float4*>(ew + i);
        float h0 = h[(size_t)c0.x * 64 + lane];
        float h1 = h[(size_t)c0.y * 64 + lane];
        float h2 = h[(size_t)c0.z * 64 + lane];
        float h3 = h[(size_t)c0.w * 64 + lane];
        denom += (w0.x + w0.y) + (w0.z + w0.w);
        acc = fmaf(h0, w0.x, acc);
        acc = fmaf(h1, w0.y, acc);
        acc = fmaf(h2, w0.z, acc);
        acc = fmaf(h3, w0.w, acc);
    }
    for (; i < end; ++i) {
        float w = ew[i];
        denom += w;
        acc = fmaf(h[(size_t)colv[i] * 64 + lane], w, acc);
    }

    float o = acc / denom + bias[lane];
    if (ELU) o = o > 0.f ? o : __expf(o) - 1.f;
    out[(size_t)node * 64 + lane] = o;
}

// ---------------- Launch ----------------

extern "C" void kernel_launch(void* const* d_in, const int* in_sizes, int n_in,
                              void* d_out, int out_size, void* d_ws, size_t ws_size,
                              hipStream_t stream) {
    const float* x    = (const float*)d_in[0];
    const int*   eidx = (const int*)d_in[1];   // [2, E] flat
    const float* W1   = (const float*)d_in[2];
    const float* aS1  = (const float*)d_in[3];
    const float* aD1  = (const float*)d_in[4];
    const float* b1   = (const float*)d_in[5];
    const float* W2   = (const float*)d_in[6];
    const float* aS2  = (const float*)d_in[7];
    const float* aD2  = (const float*)d_in[8];
    const float* b2   = (const float*)d_in[9];
    float* out = (float*)d_out;

    const int F = 128, H = 64;
    const int N = in_sizes[0] / F;
    const int E = in_sizes[1] / 2;
    const int* src = eidx;
    const int* dst = eidx + E;

    // workspace carve-up
    char* p = (char*)d_ws;
    float* hbuf = (float*)p;              p += (size_t)N * H * sizeof(float);
    float* as_b = (float*)p;              p += (size_t)N * sizeof(float);
    float* ad_b = (float*)p;              p += (size_t)N * sizeof(float);
    int* deg      = (int*)p;              p += (size_t)N * sizeof(int);
    int* rowstart = (int*)p;              p += (size_t)(N + 1) * sizeof(int);
    int* colv     = (int*)p;              p += (size_t)E * sizeof(int);
    int* dstv     = (int*)p;              p += (size_t)E * sizeof(int);
    float* ewb    = (float*)p;            p += (size_t)E * sizeof(float);
    int nb = (N + SCAN_TILE - 1) / SCAN_TILE;
    int* bsum   = (int*)p;                p += (size_t)nb * sizeof(int);
    int* bsoff  = (int*)p;                p += (size_t)nb * sizeof(int);
    int NB = (N + (1 << BSH) - 1) >> BSH;           // buckets (<= 256)
    int* bhist  = (int*)p;                p += (size_t)NB * sizeof(int);
    int* boff   = (int*)p;                p += (size_t)(NB + 1) * sizeof(int);
    int* bcur   = (int*)p;                p += (size_t)NB * sizeof(int);
    // ebuf aliases hbuf: CSR build fully precedes proj1's first h write.
    unsigned* ebuf = (unsigned*)hbuf;

    int ngrid4 = (N + 3) / 4;
    int nbE = (E + EPB - 1) / EPB;
    int egrid = (E + 255) / 256;
    int nchunk = (N + 15) / 16;
    int pgrid = nchunk < 768 ? nchunk : 768;

    // --- bucketed CSR build ---
    hipMemsetAsync(bhist, 0, (size_t)NB * sizeof(int), stream);
    hipLaunchKernelGGL(bucket_hist_kernel, dim3(nbE), dim3(256), 0, stream, dst, bhist, E, NB);
    hipLaunchKernelGGL(bucket_scan_kernel, dim3(1), dim3(256), 0, stream, bhist, boff, bcur, NB);
    hipLaunchKernelGGL(bucket_scatter_kernel, dim3(nbE), dim3(256), 0, stream, src, dst, bcur, ebuf, E);
    hipLaunchKernelGGL(deg_count_kernel, dim3(NB), dim3(256), 0, stream, ebuf, boff, deg, N);
    hipLaunchKernelGGL(blocksum_kernel, dim3(nb), dim3(256), 0, stream, deg, bsum, N);
    hipLaunchKernelGGL(scan_bsum_kernel, dim3(1), dim3(1024), 0, stream, bsum, bsoff, rowstart + N, nb);
    hipLaunchKernelGGL(scan_final_kernel, dim3(nb), dim3(256), 0, stream, deg, bsoff, rowstart, N);
    hipLaunchKernelGGL(final_scatter_kernel, dim3(NB), dim3(256), 0, stream, ebuf, boff, rowstart, colv, dstv, N);

    // --- layer 1 ---
    hipLaunchKernelGGL((proj_kernel<128>), dim3(pgrid), dim3(256), 0, stream,
                       x, W1, aS1, aD1, hbuf, as_b, ad_b, N);
    hipLaunchKernelGGL(edge_weight_kernel, dim3(egrid), dim3(256), 0, stream,
                       colv, dstv, as_b, ad_b, ewb, E);
    hipLaunchKernelGGL((agg_kernel<true>), dim3(ngrid4), dim3(256), 0, stream,
                       hbuf, ewb, colv, as_b, ad_b, rowstart, b1, out, N);

    // --- layer 2 ---
    hipLaunchKernelGGL((proj_kernel<64>), dim3(pgrid), dim3(256), 0, stream,
                       out, W2, aS2, aD2, hbuf, as_b, ad_b, N);
    hipLaunchKernelGGL(edge_weight_kernel, dim3(egrid), dim3(256), 0, stream,
                       colv, dstv, as_b, ad_b, ewb, E);
    hipLaunchKernelGGL((agg_kernel<false>), dim3(ngrid4), dim3(256), 0, stream,
                       hbuf, ewb, colv, as_b, ad_b, rowstart, b2, out, N);
}

// Round 12
// 196.792 us; speedup vs baseline: 1.0861x; 1.0861x over previous
//
#include <hip/hip_runtime.h>
#include <hip/hip_bf16.h>

#define LRELU(x) ((x) > 0.f ? (x) : 0.2f * (x))
#define SCAN_TILE 1024
#define BSH 8          // bucket = 256 consecutive dst nodes (requires N < 131072)
#define EPB 4096       // edges per block in bucket phases

// ---------------- Bucketed CSR build ----------------
// Edge packing: bits [0,17) = src, bits [17,25) = dst & 255; bucket implicit in slab.

__global__ void bucket_hist_kernel(const int* __restrict__ dst, int* __restrict__ bhist,
                                   int E, int NB) {
    __shared__ int cnt[256];
    int t = threadIdx.x;
    cnt[t] = 0;
    __syncthreads();
    int e0 = blockIdx.x * EPB + t;
#pragma unroll
    for (int i = 0; i < EPB / 256; ++i) {
        int e = e0 + i * 256;
        if (e < E) atomicAdd(&cnt[dst[e] >> BSH], 1);
    }
    __syncthreads();
    if (t < NB && cnt[t]) atomicAdd(&bhist[t], cnt[t]);
}

__global__ void bucket_scan_kernel(const int* __restrict__ bhist, int* __restrict__ boff,
                                   int* __restrict__ bcur, int NB) {
    int t = threadIdx.x;
    int v = (t < NB) ? bhist[t] : 0;
    int lane = t & 63, wid = t >> 6;
    int x = v;
#pragma unroll
    for (int off = 1; off < 64; off <<= 1) {
        int y = __shfl_up(x, off, 64);
        if (lane >= off) x += y;
    }
    __shared__ int sw[4], sw2[4];
    if (lane == 63) sw[wid] = x;
    __syncthreads();
    if (t == 0) { int a = 0; for (int w = 0; w < 4; ++w) { sw2[w] = a; a += sw[w]; } }
    __syncthreads();
    int excl = x - v + sw2[wid];
    if (t < NB) { boff[t] = excl; bcur[t] = excl; }
    if (t == NB - 1) boff[NB] = excl + v;   // == E
}

__global__ void bucket_scatter_kernel(const int* __restrict__ src, const int* __restrict__ dst,
                                      int* __restrict__ bcur, unsigned* __restrict__ ebuf, int E) {
    __shared__ int cnt[256];
    __shared__ int base[256];
    int t = threadIdx.x;
    cnt[t] = 0;
    __syncthreads();
    unsigned pk[EPB / 256];
    int bb[EPB / 256];
    int e0 = blockIdx.x * EPB + t;
#pragma unroll
    for (int i = 0; i < EPB / 256; ++i) {
        int e = e0 + i * 256;
        int b = -1; unsigned p = 0;
        if (e < E) {
            int s = src[e], d = dst[e];
            b = d >> BSH;
            p = (unsigned)s | ((unsigned)(d & ((1 << BSH) - 1)) << 17);
            atomicAdd(&cnt[b], 1);
        }
        bb[i] = b; pk[i] = p;
    }
    __syncthreads();
    if (cnt[t]) base[t] = atomicAdd(&bcur[t], cnt[t]);
    __syncthreads();
    cnt[t] = 0;
    __syncthreads();
#pragma unroll
    for (int i = 0; i < EPB / 256; ++i) {
        if (bb[i] >= 0) {
            int pos = base[bb[i]] + atomicAdd(&cnt[bb[i]], 1);
            ebuf[pos] = pk[i];
        }
    }
}

__global__ void deg_count_kernel(const unsigned* __restrict__ ebuf, const int* __restrict__ boff,
                                 int* __restrict__ deg, int n) {
    __shared__ int cnt[256];
    int t = threadIdx.x, b = blockIdx.x;
    cnt[t] = 0;
    __syncthreads();
    int beg = boff[b], end = boff[b + 1];
    for (int j = beg + t; j < end; j += 256)
        atomicAdd(&cnt[(ebuf[j] >> 17) & 255], 1);
    __syncthreads();
    int node = (b << BSH) + t;
    if (node < n) deg[node] = cnt[t];
}

__global__ void blocksum_kernel(const int* __restrict__ deg, int* __restrict__ bsum, int n) {
    int t = threadIdx.x;
    int i0 = blockIdx.x * SCAN_TILE + t * 4;
    int v = 0;
    if (i0 + 3 < n) {
        int4 q = *reinterpret_cast<const int4*>(deg + i0);
        v = q.x + q.y + q.z + q.w;
    } else {
#pragma unroll
        for (int k = 0; k < 4; ++k) if (i0 + k < n) v += deg[i0 + k];
    }
#pragma unroll
    for (int off = 32; off; off >>= 1) v += __shfl_xor(v, off, 64);
    __shared__ int sw[4];
    int lane = t & 63, wid = t >> 6;
    if (lane == 0) sw[wid] = v;
    __syncthreads();
    if (t == 0) bsum[blockIdx.x] = sw[0] + sw[1] + sw[2] + sw[3];
}

__global__ void scan_bsum_kernel(const int* __restrict__ bsum, int* __restrict__ boff,
                                 int* __restrict__ total_out, int nb) {
    int t = threadIdx.x;  // 1024 threads
    int v = (t < nb) ? bsum[t] : 0;
    int lane = t & 63, wid = t >> 6;
    int x = v;
#pragma unroll
    for (int off = 1; off < 64; off <<= 1) {
        int y = __shfl_up(x, off, 64);
        if (lane >= off) x += y;
    }
    __shared__ int sw[16], sw2[16];
    if (lane == 63) sw[wid] = x;
    __syncthreads();
    if (t == 0) {
        int a = 0;
#pragma unroll
        for (int w = 0; w < 16; ++w) { sw2[w] = a; a += sw[w]; }
    }
    __syncthreads();
    int incl = x + sw2[wid];
    if (t < nb) boff[t] = incl - v;
    if (t == nb - 1) *total_out = incl;
}

__global__ void scan_final_kernel(const int* __restrict__ deg, const int* __restrict__ boff,
                                  int* __restrict__ rowstart, int n) {
    int t = threadIdx.x;
    int i0 = blockIdx.x * SCAN_TILE + t * 4;
    int v0 = 0, v1 = 0, v2 = 0, v3 = 0;
    if (i0 + 3 < n) {
        int4 q = *reinterpret_cast<const int4*>(deg + i0);
        v0 = q.x; v1 = q.y; v2 = q.z; v3 = q.w;
    } else {
        if (i0     < n) v0 = deg[i0];
        if (i0 + 1 < n) v1 = deg[i0 + 1];
        if (i0 + 2 < n) v2 = deg[i0 + 2];
        if (i0 + 3 < n) v3 = deg[i0 + 3];
    }
    int tsum = v0 + v1 + v2 + v3;
    int lane = t & 63, wid = t >> 6;
    int x = tsum;
#pragma unroll
    for (int off = 1; off < 64; off <<= 1) {
        int y = __shfl_up(x, off, 64);
        if (lane >= off) x += y;
    }
    __shared__ int sw[4], sw2[4];
    if (lane == 63) sw[wid] = x;
    __syncthreads();
    if (t == 0) {
        int a = 0;
#pragma unroll
        for (int w = 0; w < 4; ++w) { sw2[w] = a; a += sw[w]; }
    }
    __syncthreads();
    int excl = x - tsum + sw2[wid] + boff[blockIdx.x];
    int e0 = excl, e1 = e0 + v0, e2 = e1 + v1, e3 = e2 + v2;
    if (i0     < n) rowstart[i0]     = e0;
    if (i0 + 1 < n) rowstart[i0 + 1] = e1;
    if (i0 + 2 < n) rowstart[i0 + 2] = e2;
    if (i0 + 3 < n) rowstart[i0 + 3] = e3;
}

// Phase F: per-bucket final scatter. LDS cursors; colv writes confined to the
// bucket's ~16KB contiguous region.
__global__ void final_scatter_kernel(const unsigned* __restrict__ ebuf, const int* __restrict__ boff,
                                     const int* __restrict__ rowstart, int* __restrict__ colv, int n) {
    __shared__ int cur[256];
    int t = threadIdx.x, b = blockIdx.x;
    int node = (b << BSH) + t;
    if (node < n) cur[t] = rowstart[node];
    __syncthreads();
    int beg = boff[b], end = boff[b + 1];
    for (int j = beg + t; j < end; j += 256) {
        unsigned p = ebuf[j];
        int dlow = (p >> 17) & 255;
        int s = (int)(p & 0x1FFFF);
        int pos = atomicAdd(&cur[dlow], 1);
        colv[pos] = s;
    }
}

// ---------------- Projection: h(bf16) = x @ W (+ fused h.a_src / h.a_dst reductions) ----------------
// h stored as bf16: halves the gather bytes in agg (the measured bottleneck: each
// XCD's L2 re-fetches ~the whole h buffer; 83 MB -> ~42 MB per agg dispatch).

template <int K>
__global__ __launch_bounds__(256, 3) void proj_kernel(
        const float* __restrict__ x, const float* __restrict__ W,
        const float* __restrict__ a_src, const float* __restrict__ a_dst,
        __hip_bfloat16* __restrict__ h, float* __restrict__ as_out,
        float* __restrict__ ad_out, int n) {
    __shared__ float Wt[64 * (K + 1)];   // [col][k], stride K+1
    __shared__ float xsh[16 * K];        // 16-row chunk

    for (int i = threadIdx.x; i < K * 64; i += 256) {
        int k = i >> 6, c = i & 63;
        Wt[c * (K + 1) + k] = W[i];
    }

    int lane = threadIdx.x & 63, wid = threadIdx.x >> 6;
    float as_l = a_src[lane], ad_l = a_dst[lane];
    const float4* x4 = reinterpret_cast<const float4*>(x);
    float4* xsh4 = reinterpret_cast<float4*>(xsh);
    const int K4 = K / 4;
    int nchunk = (n + 15) >> 4;

    for (int ci = blockIdx.x; ci < nchunk; ci += gridDim.x) {
        int base = ci * 16;
        __syncthreads();
        for (int j = threadIdx.x; j < 16 * K4; j += 256) {
            int row = j / K4;
            int r = base + row;
            float4 v = make_float4(0.f, 0.f, 0.f, 0.f);
            if (r < n) v = x4[(size_t)r * K4 + (j - row * K4)];
            xsh4[j] = v;
        }
        __syncthreads();

        int r0 = base + wid * 4;
        float acc0 = 0.f, acc1 = 0.f, acc2 = 0.f, acc3 = 0.f;
        const float* wl = Wt + lane * (K + 1);
#pragma unroll 4
        for (int k4 = 0; k4 < K4; ++k4) {
            float4 va = xsh4[(wid * 4 + 0) * K4 + k4];
            float4 vb = xsh4[(wid * 4 + 1) * K4 + k4];
            float4 vc = xsh4[(wid * 4 + 2) * K4 + k4];
            float4 vd = xsh4[(wid * 4 + 3) * K4 + k4];
            float w0 = wl[k4 * 4 + 0];
            float w1 = wl[k4 * 4 + 1];
            float w2 = wl[k4 * 4 + 2];
            float w3 = wl[k4 * 4 + 3];
            acc0 = fmaf(va.x, w0, acc0); acc0 = fmaf(va.y, w1, acc0);
            acc0 = fmaf(va.z, w2, acc0); acc0 = fmaf(va.w, w3, acc0);
            acc1 = fmaf(vb.x, w0, acc1); acc1 = fmaf(vb.y, w1, acc1);
            acc1 = fmaf(vb.z, w2, acc1); acc1 = fmaf(vb.w, w3, acc1);
            acc2 = fmaf(vc.x, w0, acc2); acc2 = fmaf(vc.y, w1, acc2);
            acc2 = fmaf(vc.z, w2, acc2); acc2 = fmaf(vc.w, w3, acc2);
            acc3 = fmaf(vd.x, w0, acc3); acc3 = fmaf(vd.y, w1, acc3);
            acc3 = fmaf(vd.z, w2, acc3); acc3 = fmaf(vd.w, w3, acc3);
        }
        if (r0 + 0 < n) h[(size_t)(r0 + 0) * 64 + lane] = __float2bfloat16(acc0);
        if (r0 + 1 < n) h[(size_t)(r0 + 1) * 64 + lane] = __float2bfloat16(acc1);
        if (r0 + 2 < n) h[(size_t)(r0 + 2) * 64 + lane] = __float2bfloat16(acc2);
        if (r0 + 3 < n) h[(size_t)(r0 + 3) * 64 + lane] = __float2bfloat16(acc3);
        float s0 = acc0 * as_l, d0 = acc0 * ad_l;
        float s1 = acc1 * as_l, d1 = acc1 * ad_l;
        float s2 = acc2 * as_l, d2 = acc2 * ad_l;
        float s3 = acc3 * as_l, d3 = acc3 * ad_l;
#pragma unroll
        for (int off = 32; off; off >>= 1) {
            s0 += __shfl_xor(s0, off, 64); d0 += __shfl_xor(d0, off, 64);
            s1 += __shfl_xor(s1, off, 64); d1 += __shfl_xor(d1, off, 64);
            s2 += __shfl_xor(s2, off, 64); d2 += __shfl_xor(d2, off, 64);
            s3 += __shfl_xor(s3, off, 64); d3 += __shfl_xor(d3, off, 64);
        }
        if (lane == 0) {
            if (r0 + 0 < n) { as_out[r0 + 0] = s0; ad_out[r0 + 0] = d0; }
            if (r0 + 1 < n) { as_out[r0 + 1] = s1; ad_out[r0 + 1] = d1; }
            if (r0 + 2 < n) { as_out[r0 + 2] = s2; ad_out[r0 + 2] = d2; }
            if (r0 + 3 < n) { as_out[r0 + 3] = s3; ad_out[r0 + 3] = d3; }
        }
    }
}

// ---------------- Aggregation: fused single-pass softmax + bf16 weighted gather-sum ----------
// One wave per node, lane = feature. 8 edges in flight: aligned int4 colv loads,
// 8 independent as-broadcasts, 8 independent 128B bf16 row-gathers.

template <bool ELU>
__global__ void agg_kernel(const __hip_bfloat16* __restrict__ h, const float* __restrict__ as_in,
                           const float* __restrict__ ad_in, const int* __restrict__ rowstart,
                           const int* __restrict__ colv, const float* __restrict__ bias,
                           float* __restrict__ out, int n) {
    int node = blockIdx.x * 4 + (threadIdx.x >> 6);
    int lane = threadIdx.x & 63;
    if (node >= n) return;

    float ad_n = ad_in[node];
    int beg = rowstart[node], end = rowstart[node + 1];

    // self-loop
    float ex = __expf(LRELU(as_in[node] + ad_n));
    float denom = ex;
    float acc = __bfloat162float(h[(size_t)node * 64 + lane]) * ex;

    int i = beg;
    int aligned = (beg + 3) & ~3;
    if (aligned > end) aligned = end;
    for (; i < aligned; ++i) {
        int s = colv[i];
        float w = __expf(LRELU(as_in[s] + ad_n));
        denom += w;
        acc = fmaf(__bfloat162float(h[(size_t)s * 64 + lane]), w, acc);
    }
    for (; i + 7 < end; i += 8) {
        int4 c0 = *reinterpret_cast<const int4*>(colv + i);
        int4 c1 = *reinterpret_cast<const int4*>(colv + i + 4);
        float a0 = as_in[c0.x], a1 = as_in[c0.y], a2 = as_in[c0.z], a3 = as_in[c0.w];
        float a4 = as_in[c1.x], a5 = as_in[c1.y], a6 = as_in[c1.z], a7 = as_in[c1.w];
        float h0 = __bfloat162float(h[(size_t)c0.x * 64 + lane]);
        float h1 = __bfloat162float(h[(size_t)c0.y * 64 + lane]);
        float h2 = __bfloat162float(h[(size_t)c0.z * 64 + lane]);
        float h3 = __bfloat162float(h[(size_t)c0.w * 64 + lane]);
        float h4 = __bfloat162float(h[(size_t)c1.x * 64 + lane]);
        float h5 = __bfloat162float(h[(size_t)c1.y * 64 + lane]);
        float h6 = __bfloat162float(h[(size_t)c1.z * 64 + lane]);
        float h7 = __bfloat162float(h[(size_t)c1.w * 64 + lane]);
        float x0 = __expf(LRELU(a0 + ad_n));
        float x1 = __expf(LRELU(a1 + ad_n));
        float x2 = __expf(LRELU(a2 + ad_n));
        float x3 = __expf(LRELU(a3 + ad_n));
        float x4 = __expf(LRELU(a4 + ad_n));
        float x5 = __expf(LRELU(a5 + ad_n));
        float x6 = __expf(LRELU(a6 + ad_n));
        float x7 = __expf(LRELU(a7 + ad_n));
        denom += ((x0 + x1) + (x2 + x3)) + ((x4 + x5) + (x6 + x7));
        acc = fmaf(h0, x0, acc);
        acc = fmaf(h1, x1, acc);
        acc = fmaf(h2, x2, acc);
        acc = fmaf(h3, x3, acc);
        acc = fmaf(h4, x4, acc);
        acc = fmaf(h5, x5, acc);
        acc = fmaf(h6, x6, acc);
        acc = fmaf(h7, x7, acc);
    }
    for (; i + 3 < end; i += 4) {
        int4 c0 = *reinterpret_cast<const int4*>(colv + i);
        float a0 = as_in[c0.x], a1 = as_in[c0.y], a2 = as_in[c0.z], a3 = as_in[c0.w];
        float h0 = __bfloat162float(h[(size_t)c0.x * 64 + lane]);
        float h1 = __bfloat162float(h[(size_t)c0.y * 64 + lane]);
        float h2 = __bfloat162float(h[(size_t)c0.z * 64 + lane]);
        float h3 = __bfloat162float(h[(size_t)c0.w * 64 + lane]);
        float x0 = __expf(LRELU(a0 + ad_n));
        float x1 = __expf(LRELU(a1 + ad_n));
        float x2 = __expf(LRELU(a2 + ad_n));
        float x3 = __expf(LRELU(a3 + ad_n));
        denom += (x0 + x1) + (x2 + x3);
        acc = fmaf(h0, x0, acc);
        acc = fmaf(h1, x1, acc);
        acc = fmaf(h2, x2, acc);
        acc = fmaf(h3, x3, acc);
    }
    for (; i < end; ++i) {
        int s = colv[i];
        float w = __expf(LRELU(as_in[s] + ad_n));
        denom += w;
        acc = fmaf(__bfloat162float(h[(size_t)s * 64 + lane]), w, acc);
    }

    float o = acc / denom + bias[lane];
    if (ELU) o = o > 0.f ? o : __expf(o) - 1.f;
    out[(size_t)node * 64 + lane] = o;
}

// ---------------- Launch ----------------

extern "C" void kernel_launch(void* const* d_in, const int* in_sizes, int n_in,
                              void* d_out, int out_size, void* d_ws, size_t ws_size,
                              hipStream_t stream) {
    const float* x    = (const float*)d_in[0];
    const int*   eidx = (const int*)d_in[1];   // [2, E] flat
    const float* W1   = (const float*)d_in[2];
    const float* aS1  = (const float*)d_in[3];
    const float* aD1  = (const float*)d_in[4];
    const float* b1   = (const float*)d_in[5];
    const float* W2   = (const float*)d_in[6];
    const float* aS2  = (const float*)d_in[7];
    const float* aD2  = (const float*)d_in[8];
    const float* b2   = (const float*)d_in[9];
    float* out = (float*)d_out;

    const int F = 128, H = 64;
    const int N = in_sizes[0] / F;
    const int E = in_sizes[1] / 2;
    const int* src = eidx;
    const int* dst = eidx + E;

    // workspace carve-up
    char* p = (char*)d_ws;
    __hip_bfloat16* hbuf = (__hip_bfloat16*)p;  p += (size_t)N * H * sizeof(__hip_bfloat16);
    float* as_b = (float*)p;              p += (size_t)N * sizeof(float);
    float* ad_b = (float*)p;              p += (size_t)N * sizeof(float);
    int* deg      = (int*)p;              p += (size_t)N * sizeof(int);
    int* rowstart = (int*)p;              p += (size_t)(N + 1) * sizeof(int);
    int* colv     = (int*)p;              p += (size_t)E * sizeof(int);
    int nb = (N + SCAN_TILE - 1) / SCAN_TILE;
    int* bsum   = (int*)p;                p += (size_t)nb * sizeof(int);
    int* bsoff  = (int*)p;                p += (size_t)nb * sizeof(int);
    int NB = (N + (1 << BSH) - 1) >> BSH;           // buckets (<= 256)
    int* bhist  = (int*)p;                p += (size_t)NB * sizeof(int);
    int* boff   = (int*)p;                p += (size_t)(NB + 1) * sizeof(int);
    int* bcur   = (int*)p;                p += (size_t)NB * sizeof(int);
    // ebuf aliases hbuf (E*4 B <= N*H*2 B): CSR build fully precedes proj1's h writes.
    unsigned* ebuf = (unsigned*)hbuf;

    int ngrid4 = (N + 3) / 4;
    int nbE = (E + EPB - 1) / EPB;
    int nchunk = (N + 15) / 16;
    int pgrid = nchunk < 768 ? nchunk : 768;

    // --- bucketed CSR build ---
    hipMemsetAsync(bhist, 0, (size_t)NB * sizeof(int), stream);
    hipLaunchKernelGGL(bucket_hist_kernel, dim3(nbE), dim3(256), 0, stream, dst, bhist, E, NB);
    hipLaunchKernelGGL(bucket_scan_kernel, dim3(1), dim3(256), 0, stream, bhist, boff, bcur, NB);
    hipLaunchKernelGGL(bucket_scatter_kernel, dim3(nbE), dim3(256), 0, stream, src, dst, bcur, ebuf, E);
    hipLaunchKernelGGL(deg_count_kernel, dim3(NB), dim3(256), 0, stream, ebuf, boff, deg, N);
    hipLaunchKernelGGL(blocksum_kernel, dim3(nb), dim3(256), 0, stream, deg, bsum, N);
    hipLaunchKernelGGL(scan_bsum_kernel, dim3(1), dim3(1024), 0, stream, bsum, bsoff, rowstart + N, nb);
    hipLaunchKernelGGL(scan_final_kernel, dim3(nb), dim3(256), 0, stream, deg, bsoff, rowstart, N);
    hipLaunchKernelGGL(final_scatter_kernel, dim3(NB), dim3(256), 0, stream, ebuf, boff, rowstart, colv, N);

    // --- layer 1 ---
    hipLaunchKernelGGL((proj_kernel<128>), dim3(pgrid), dim3(256), 0, stream,
                       x, W1, aS1, aD1, hbuf, as_b, ad_b, N);
    hipLaunchKernelGGL((agg_kernel<true>), dim3(ngrid4), dim3(256), 0, stream,
                       hbuf, as_b, ad_b, rowstart, colv, b1, out, N);

    // --- layer 2 ---
    hipLaunchKernelGGL((proj_kernel<64>), dim3(pgrid), dim3(256), 0, stream,
                       out, W2, aS2, aD2, hbuf, as_b, ad_b, N);
    hipLaunchKernelGGL((agg_kernel<false>), dim3(ngrid4), dim3(256), 0, stream,
                       hbuf, as_b, ad_b, rowstart, colv, b2, out, N);
}

// Round 13
// 186.170 us; speedup vs baseline: 1.1481x; 1.0571x over previous
//
#include <hip/hip_runtime.h>
#include <hip/hip_bf16.h>

#define LRELU(x) ((x) > 0.f ? (x) : 0.2f * (x))
#define SCAN_TILE 1024
#define BSH 8          // bucket = 256 consecutive dst nodes (requires N < 131072)
#define EPB 4096       // edges per block in bucket phases

// ---------------- Bucketed CSR build ----------------
// Edge packing: bits [0,17) = src, bits [17,25) = dst & 255; bucket implicit in slab.

__global__ void bucket_hist_kernel(const int* __restrict__ dst, int* __restrict__ bhist,
                                   int E, int NB) {
    __shared__ int cnt[256];
    int t = threadIdx.x;
    cnt[t] = 0;
    __syncthreads();
    int e0 = blockIdx.x * EPB + t;
#pragma unroll
    for (int i = 0; i < EPB / 256; ++i) {
        int e = e0 + i * 256;
        if (e < E) atomicAdd(&cnt[dst[e] >> BSH], 1);
    }
    __syncthreads();
    if (t < NB && cnt[t]) atomicAdd(&bhist[t], cnt[t]);
}

__global__ void bucket_scan_kernel(const int* __restrict__ bhist, int* __restrict__ boff,
                                   int* __restrict__ bcur, int NB) {
    int t = threadIdx.x;
    int v = (t < NB) ? bhist[t] : 0;
    int lane = t & 63, wid = t >> 6;
    int x = v;
#pragma unroll
    for (int off = 1; off < 64; off <<= 1) {
        int y = __shfl_up(x, off, 64);
        if (lane >= off) x += y;
    }
    __shared__ int sw[4], sw2[4];
    if (lane == 63) sw[wid] = x;
    __syncthreads();
    if (t == 0) { int a = 0; for (int w = 0; w < 4; ++w) { sw2[w] = a; a += sw[w]; } }
    __syncthreads();
    int excl = x - v + sw2[wid];
    if (t < NB) { boff[t] = excl; bcur[t] = excl; }
    if (t == NB - 1) boff[NB] = excl + v;   // == E
}

__global__ void bucket_scatter_kernel(const int* __restrict__ src, const int* __restrict__ dst,
                                      int* __restrict__ bcur, unsigned* __restrict__ ebuf, int E) {
    __shared__ int cnt[256];
    __shared__ int base[256];
    int t = threadIdx.x;
    cnt[t] = 0;
    __syncthreads();
    unsigned pk[EPB / 256];
    int bb[EPB / 256];
    int e0 = blockIdx.x * EPB + t;
#pragma unroll
    for (int i = 0; i < EPB / 256; ++i) {
        int e = e0 + i * 256;
        int b = -1; unsigned p = 0;
        if (e < E) {
            int s = src[e], d = dst[e];
            b = d >> BSH;
            p = (unsigned)s | ((unsigned)(d & ((1 << BSH) - 1)) << 17);
            atomicAdd(&cnt[b], 1);
        }
        bb[i] = b; pk[i] = p;
    }
    __syncthreads();
    if (cnt[t]) base[t] = atomicAdd(&bcur[t], cnt[t]);
    __syncthreads();
    cnt[t] = 0;
    __syncthreads();
#pragma unroll
    for (int i = 0; i < EPB / 256; ++i) {
        if (bb[i] >= 0) {
            int pos = base[bb[i]] + atomicAdd(&cnt[bb[i]], 1);
            ebuf[pos] = pk[i];
        }
    }
}

__global__ void deg_count_kernel(const unsigned* __restrict__ ebuf, const int* __restrict__ boff,
                                 int* __restrict__ deg, int n) {
    __shared__ int cnt[256];
    int t = threadIdx.x, b = blockIdx.x;
    cnt[t] = 0;
    __syncthreads();
    int beg = boff[b], end = boff[b + 1];
    for (int j = beg + t; j < end; j += 256)
        atomicAdd(&cnt[(ebuf[j] >> 17) & 255], 1);
    __syncthreads();
    int node = (b << BSH) + t;
    if (node < n) deg[node] = cnt[t];
}

__global__ void blocksum_kernel(const int* __restrict__ deg, int* __restrict__ bsum, int n) {
    int t = threadIdx.x;
    int i0 = blockIdx.x * SCAN_TILE + t * 4;
    int v = 0;
    if (i0 + 3 < n) {
        int4 q = *reinterpret_cast<const int4*>(deg + i0);
        v = q.x + q.y + q.z + q.w;
    } else {
#pragma unroll
        for (int k = 0; k < 4; ++k) if (i0 + k < n) v += deg[i0 + k];
    }
#pragma unroll
    for (int off = 32; off; off >>= 1) v += __shfl_xor(v, off, 64);
    __shared__ int sw[4];
    int lane = t & 63, wid = t >> 6;
    if (lane == 0) sw[wid] = v;
    __syncthreads();
    if (t == 0) bsum[blockIdx.x] = sw[0] + sw[1] + sw[2] + sw[3];
}

__global__ void scan_bsum_kernel(const int* __restrict__ bsum, int* __restrict__ boff,
                                 int* __restrict__ total_out, int nb) {
    int t = threadIdx.x;  // 1024 threads
    int v = (t < nb) ? bsum[t] : 0;
    int lane = t & 63, wid = t >> 6;
    int x = v;
#pragma unroll
    for (int off = 1; off < 64; off <<= 1) {
        int y = __shfl_up(x, off, 64);
        if (lane >= off) x += y;
    }
    __shared__ int sw[16], sw2[16];
    if (lane == 63) sw[wid] = x;
    __syncthreads();
    if (t == 0) {
        int a = 0;
#pragma unroll
        for (int w = 0; w < 16; ++w) { sw2[w] = a; a += sw[w]; }
    }
    __syncthreads();
    int incl = x + sw2[wid];
    if (t < nb) boff[t] = incl - v;
    if (t == nb - 1) *total_out = incl;
}

__global__ void scan_final_kernel(const int* __restrict__ deg, const int* __restrict__ boff,
                                  int* __restrict__ rowstart, int n) {
    int t = threadIdx.x;
    int i0 = blockIdx.x * SCAN_TILE + t * 4;
    int v0 = 0, v1 = 0, v2 = 0, v3 = 0;
    if (i0 + 3 < n) {
        int4 q = *reinterpret_cast<const int4*>(deg + i0);
        v0 = q.x; v1 = q.y; v2 = q.z; v3 = q.w;
    } else {
        if (i0     < n) v0 = deg[i0];
        if (i0 + 1 < n) v1 = deg[i0 + 1];
        if (i0 + 2 < n) v2 = deg[i0 + 2];
        if (i0 + 3 < n) v3 = deg[i0 + 3];
    }
    int tsum = v0 + v1 + v2 + v3;
    int lane = t & 63, wid = t >> 6;
    int x = tsum;
#pragma unroll
    for (int off = 1; off < 64; off <<= 1) {
        int y = __shfl_up(x, off, 64);
        if (lane >= off) x += y;
    }
    __shared__ int sw[4], sw2[4];
    if (lane == 63) sw[wid] = x;
    __syncthreads();
    if (t == 0) {
        int a = 0;
#pragma unroll
        for (int w = 0; w < 4; ++w) { sw2[w] = a; a += sw[w]; }
    }
    __syncthreads();
    int excl = x - tsum + sw2[wid] + boff[blockIdx.x];
    int e0 = excl, e1 = e0 + v0, e2 = e1 + v1, e3 = e2 + v2;
    if (i0     < n) rowstart[i0]     = e0;
    if (i0 + 1 < n) rowstart[i0 + 1] = e1;
    if (i0 + 2 < n) rowstart[i0 + 2] = e2;
    if (i0 + 3 < n) rowstart[i0 + 3] = e3;
}

// Phase F: per-bucket final scatter. LDS cursors; colv writes confined to the
// bucket's ~16KB contiguous region.
__global__ void final_scatter_kernel(const unsigned* __restrict__ ebuf, const int* __restrict__ boff,
                                     const int* __restrict__ rowstart, int* __restrict__ colv, int n) {
    __shared__ int cur[256];
    int t = threadIdx.x, b = blockIdx.x;
    int node = (b << BSH) + t;
    if (node < n) cur[t] = rowstart[node];
    __syncthreads();
    int beg = boff[b], end = boff[b + 1];
    for (int j = beg + t; j < end; j += 256) {
        unsigned p = ebuf[j];
        int dlow = (p >> 17) & 255;
        int s = (int)(p & 0x1FFFF);
        int pos = atomicAdd(&cur[dlow], 1);
        colv[pos] = s;
    }
}

// ---------------- Projection: h(bf16) = x @ W (+ fused h.a_src / h.a_dst reductions) ----------------

template <int K>
__global__ __launch_bounds__(256, 3) void proj_kernel(
        const float* __restrict__ x, const float* __restrict__ W,
        const float* __restrict__ a_src, const float* __restrict__ a_dst,
        __hip_bfloat16* __restrict__ h, float* __restrict__ as_out,
        float* __restrict__ ad_out, int n) {
    __shared__ float Wt[64 * (K + 1)];   // [col][k], stride K+1
    __shared__ float xsh[16 * K];        // 16-row chunk

    for (int i = threadIdx.x; i < K * 64; i += 256) {
        int k = i >> 6, c = i & 63;
        Wt[c * (K + 1) + k] = W[i];
    }

    int lane = threadIdx.x & 63, wid = threadIdx.x >> 6;
    float as_l = a_src[lane], ad_l = a_dst[lane];
    const float4* x4 = reinterpret_cast<const float4*>(x);
    float4* xsh4 = reinterpret_cast<float4*>(xsh);
    const int K4 = K / 4;
    int nchunk = (n + 15) >> 4;

    for (int ci = blockIdx.x; ci < nchunk; ci += gridDim.x) {
        int base = ci * 16;
        __syncthreads();
        for (int j = threadIdx.x; j < 16 * K4; j += 256) {
            int row = j / K4;
            int r = base + row;
            float4 v = make_float4(0.f, 0.f, 0.f, 0.f);
            if (r < n) v = x4[(size_t)r * K4 + (j - row * K4)];
            xsh4[j] = v;
        }
        __syncthreads();

        int r0 = base + wid * 4;
        float acc0 = 0.f, acc1 = 0.f, acc2 = 0.f, acc3 = 0.f;
        const float* wl = Wt + lane * (K + 1);
#pragma unroll 4
        for (int k4 = 0; k4 < K4; ++k4) {
            float4 va = xsh4[(wid * 4 + 0) * K4 + k4];
            float4 vb = xsh4[(wid * 4 + 1) * K4 + k4];
            float4 vc = xsh4[(wid * 4 + 2) * K4 + k4];
            float4 vd = xsh4[(wid * 4 + 3) * K4 + k4];
            float w0 = wl[k4 * 4 + 0];
            float w1 = wl[k4 * 4 + 1];
            float w2 = wl[k4 * 4 + 2];
            float w3 = wl[k4 * 4 + 3];
            acc0 = fmaf(va.x, w0, acc0); acc0 = fmaf(va.y, w1, acc0);
            acc0 = fmaf(va.z, w2, acc0); acc0 = fmaf(va.w, w3, acc0);
            acc1 = fmaf(vb.x, w0, acc1); acc1 = fmaf(vb.y, w1, acc1);
            acc1 = fmaf(vb.z, w2, acc1); acc1 = fmaf(vb.w, w3, acc1);
            acc2 = fmaf(vc.x, w0, acc2); acc2 = fmaf(vc.y, w1, acc2);
            acc2 = fmaf(vc.z, w2, acc2); acc2 = fmaf(vc.w, w3, acc2);
            acc3 = fmaf(vd.x, w0, acc3); acc3 = fmaf(vd.y, w1, acc3);
            acc3 = fmaf(vd.z, w2, acc3); acc3 = fmaf(vd.w, w3, acc3);
        }
        if (r0 + 0 < n) h[(size_t)(r0 + 0) * 64 + lane] = __float2bfloat16(acc0);
        if (r0 + 1 < n) h[(size_t)(r0 + 1) * 64 + lane] = __float2bfloat16(acc1);
        if (r0 + 2 < n) h[(size_t)(r0 + 2) * 64 + lane] = __float2bfloat16(acc2);
        if (r0 + 3 < n) h[(size_t)(r0 + 3) * 64 + lane] = __float2bfloat16(acc3);
        float s0 = acc0 * as_l, d0 = acc0 * ad_l;
        float s1 = acc1 * as_l, d1 = acc1 * ad_l;
        float s2 = acc2 * as_l, d2 = acc2 * ad_l;
        float s3 = acc3 * as_l, d3 = acc3 * ad_l;
#pragma unroll
        for (int off = 32; off; off >>= 1) {
            s0 += __shfl_xor(s0, off, 64); d0 += __shfl_xor(d0, off, 64);
            s1 += __shfl_xor(s1, off, 64); d1 += __shfl_xor(d1, off, 64);
            s2 += __shfl_xor(s2, off, 64); d2 += __shfl_xor(d2, off, 64);
            s3 += __shfl_xor(s3, off, 64); d3 += __shfl_xor(d3, off, 64);
        }
        if (lane == 0) {
            if (r0 + 0 < n) { as_out[r0 + 0] = s0; ad_out[r0 + 0] = d0; }
            if (r0 + 1 < n) { as_out[r0 + 1] = s1; ad_out[r0 + 1] = d1; }
            if (r0 + 2 < n) { as_out[r0 + 2] = s2; ad_out[r0 + 2] = d2; }
            if (r0 + 3 < n) { as_out[r0 + 3] = s3; ad_out[r0 + 3] = d3; }
        }
    }
}

// ---------------- Aggregation: half-wave-paired softmax + packed-bf16 gather-sum ----------------
// One wave per node. Lanes 0-31 process even edges of each pair, lanes 32-63 odd edges;
// each lane owns a PACKED u32 = 2 bf16 features. One wave-instruction covers 2 edges
// (exp/select/gather) and 128 features (float2 fma) -> ~2x fewer VALU+VMEM instrs/edge.
// Final cross-half combine: one shfl_xor(32) per accumulator.

__device__ inline float bf_lo(unsigned w) { return __uint_as_float(w << 16); }
__device__ inline float bf_hi(unsigned w) { return __uint_as_float(w & 0xffff0000u); }

template <bool ELU>
__global__ void agg_kernel(const unsigned* __restrict__ h32, const float* __restrict__ as_in,
                           const float* __restrict__ ad_in, const int* __restrict__ rowstart,
                           const int* __restrict__ colv, const float* __restrict__ bias,
                           float* __restrict__ out, int n) {
    int node = blockIdx.x * 4 + (threadIdx.x >> 6);
    int lane = threadIdx.x & 63;
    if (node >= n) return;
    int half = lane >> 5;          // which edge of the pair
    int fl   = lane & 31;          // feature-pair index: features 2fl, 2fl+1

    float ad_n = ad_in[node];
    int beg = rowstart[node], end = rowstart[node + 1];

    float denom = 0.f;
    float2 acc = make_float2(0.f, 0.f);

    // self-loop (half 0 only; combined at the end)
    if (half == 0) {
        float ex = __expf(LRELU(as_in[node] + ad_n));
        unsigned hw = h32[(unsigned)node * 32u + fl];
        denom = ex;
        acc.x = bf_lo(hw) * ex;
        acc.y = bf_hi(hw) * ex;
    }

#define PAIR_STEP(sA, sB)                                             \
    {                                                                 \
        int s_ = half ? (sB) : (sA);                                  \
        bool valid_ = s_ >= 0;                                        \
        int ss_ = valid_ ? s_ : node;                                 \
        float a_ = as_in[ss_];                                        \
        unsigned hw_ = h32[(unsigned)ss_ * 32u + fl];                 \
        float t_ = a_ + ad_n;                                         \
        float xw_ = valid_ ? __expf(LRELU(t_)) : 0.f;                 \
        denom += xw_;                                                 \
        acc.x = fmaf(bf_lo(hw_), xw_, acc.x);                         \
        acc.y = fmaf(bf_hi(hw_), xw_, acc.y);                         \
    }

    int i = beg;
    int pre = (beg + 3) & ~3;
    if (pre > end) pre = end;
    while (i < pre) {               // align to 4 for int4 loads
        int sA = colv[i];
        bool two = (i + 1 < pre);
        int sB = two ? colv[i + 1] : -1;
        PAIR_STEP(sA, sB);
        i += two ? 2 : 1;
    }
    for (; i + 7 < end; i += 8) {   // 8 edges = 4 pair-slots, 2 aligned int4 loads
        int4 cA = *reinterpret_cast<const int4*>(colv + i);
        int4 cB = *reinterpret_cast<const int4*>(colv + i + 4);
        int s0 = half ? cA.y : cA.x;
        int s1 = half ? cA.w : cA.z;
        int s2 = half ? cB.y : cB.x;
        int s3 = half ? cB.w : cB.z;
        float a0 = as_in[s0], a1 = as_in[s1], a2 = as_in[s2], a3 = as_in[s3];
        unsigned w0 = h32[(unsigned)s0 * 32u + fl];
        unsigned w1 = h32[(unsigned)s1 * 32u + fl];
        unsigned w2 = h32[(unsigned)s2 * 32u + fl];
        unsigned w3 = h32[(unsigned)s3 * 32u + fl];
        float x0 = __expf(LRELU(a0 + ad_n));
        float x1 = __expf(LRELU(a1 + ad_n));
        float x2 = __expf(LRELU(a2 + ad_n));
        float x3 = __expf(LRELU(a3 + ad_n));
        denom += (x0 + x1) + (x2 + x3);
        acc.x = fmaf(bf_lo(w0), x0, acc.x); acc.y = fmaf(bf_hi(w0), x0, acc.y);
        acc.x = fmaf(bf_lo(w1), x1, acc.x); acc.y = fmaf(bf_hi(w1), x1, acc.y);
        acc.x = fmaf(bf_lo(w2), x2, acc.x); acc.y = fmaf(bf_hi(w2), x2, acc.y);
        acc.x = fmaf(bf_lo(w3), x3, acc.x); acc.y = fmaf(bf_hi(w3), x3, acc.y);
    }
    for (; i + 3 < end; i += 4) {   // 4 edges = 2 pair-slots
        int4 cA = *reinterpret_cast<const int4*>(colv + i);
        int s0 = half ? cA.y : cA.x;
        int s1 = half ? cA.w : cA.z;
        float a0 = as_in[s0], a1 = as_in[s1];
        unsigned w0 = h32[(unsigned)s0 * 32u + fl];
        unsigned w1 = h32[(unsigned)s1 * 32u + fl];
        float x0 = __expf(LRELU(a0 + ad_n));
        float x1 = __expf(LRELU(a1 + ad_n));
        denom += x0 + x1;
        acc.x = fmaf(bf_lo(w0), x0, acc.x); acc.y = fmaf(bf_hi(w0), x0, acc.y);
        acc.x = fmaf(bf_lo(w1), x1, acc.x); acc.y = fmaf(bf_hi(w1), x1, acc.y);
    }
    while (i < end) {               // tail
        int sA = colv[i];
        bool two = (i + 1 < end);
        int sB = two ? colv[i + 1] : -1;
        PAIR_STEP(sA, sB);
        i += two ? 2 : 1;
    }
#undef PAIR_STEP

    // combine the two halves
    denom += __shfl_xor(denom, 32, 64);
    acc.x += __shfl_xor(acc.x, 32, 64);
    acc.y += __shfl_xor(acc.y, 32, 64);

    float2 bv = *reinterpret_cast<const float2*>(bias + 2 * fl);
    float ox = acc.x / denom + bv.x;
    float oy = acc.y / denom + bv.y;
    if (ELU) {
        ox = ox > 0.f ? ox : __expf(ox) - 1.f;
        oy = oy > 0.f ? oy : __expf(oy) - 1.f;
    }
    if (half == 0)
        *reinterpret_cast<float2*>(out + (size_t)node * 64 + 2 * fl) = make_float2(ox, oy);
}

// ---------------- Launch ----------------

extern "C" void kernel_launch(void* const* d_in, const int* in_sizes, int n_in,
                              void* d_out, int out_size, void* d_ws, size_t ws_size,
                              hipStream_t stream) {
    const float* x    = (const float*)d_in[0];
    const int*   eidx = (const int*)d_in[1];   // [2, E] flat
    const float* W1   = (const float*)d_in[2];
    const float* aS1  = (const float*)d_in[3];
    const float* aD1  = (const float*)d_in[4];
    const float* b1   = (const float*)d_in[5];
    const float* W2   = (const float*)d_in[6];
    const float* aS2  = (const float*)d_in[7];
    const float* aD2  = (const float*)d_in[8];
    const float* b2   = (const float*)d_in[9];
    float* out = (float*)d_out;

    const int F = 128, H = 64;
    const int N = in_sizes[0] / F;
    const int E = in_sizes[1] / 2;
    const int* src = eidx;
    const int* dst = eidx + E;

    // workspace carve-up
    char* p = (char*)d_ws;
    __hip_bfloat16* hbuf = (__hip_bfloat16*)p;  p += (size_t)N * H * sizeof(__hip_bfloat16);
    float* as_b = (float*)p;              p += (size_t)N * sizeof(float);
    float* ad_b = (float*)p;              p += (size_t)N * sizeof(float);
    int* deg      = (int*)p;              p += (size_t)N * sizeof(int);
    int* rowstart = (int*)p;              p += (size_t)(N + 1) * sizeof(int);
    int* colv     = (int*)p;              p += (size_t)E * sizeof(int);
    int nb = (N + SCAN_TILE - 1) / SCAN_TILE;
    int* bsum   = (int*)p;                p += (size_t)nb * sizeof(int);
    int* bsoff  = (int*)p;                p += (size_t)nb * sizeof(int);
    int NB = (N + (1 << BSH) - 1) >> BSH;           // buckets (<= 256)
    int* bhist  = (int*)p;                p += (size_t)NB * sizeof(int);
    int* boff   = (int*)p;                p += (size_t)(NB + 1) * sizeof(int);
    int* bcur   = (int*)p;                p += (size_t)NB * sizeof(int);
    // ebuf aliases hbuf (E*4 B <= N*H*2 B): CSR build fully precedes proj1's h writes.
    unsigned* ebuf = (unsigned*)hbuf;

    int ngrid4 = (N + 3) / 4;
    int nbE = (E + EPB - 1) / EPB;
    int nchunk = (N + 15) / 16;
    int pgrid = nchunk < 768 ? nchunk : 768;

    // --- bucketed CSR build ---
    hipMemsetAsync(bhist, 0, (size_t)NB * sizeof(int), stream);
    hipLaunchKernelGGL(bucket_hist_kernel, dim3(nbE), dim3(256), 0, stream, dst, bhist, E, NB);
    hipLaunchKernelGGL(bucket_scan_kernel, dim3(1), dim3(256), 0, stream, bhist, boff, bcur, NB);
    hipLaunchKernelGGL(bucket_scatter_kernel, dim3(nbE), dim3(256), 0, stream, src, dst, bcur, ebuf, E);
    hipLaunchKernelGGL(deg_count_kernel, dim3(NB), dim3(256), 0, stream, ebuf, boff, deg, N);
    hipLaunchKernelGGL(blocksum_kernel, dim3(nb), dim3(256), 0, stream, deg, bsum, N);
    hipLaunchKernelGGL(scan_bsum_kernel, dim3(1), dim3(1024), 0, stream, bsum, bsoff, rowstart + N, nb);
    hipLaunchKernelGGL(scan_final_kernel, dim3(nb), dim3(256), 0, stream, deg, bsoff, rowstart, N);
    hipLaunchKernelGGL(final_scatter_kernel, dim3(NB), dim3(256), 0, stream, ebuf, boff, rowstart, colv, N);

    // --- layer 1 ---
    hipLaunchKernelGGL((proj_kernel<128>), dim3(pgrid), dim3(256), 0, stream,
                       x, W1, aS1, aD1, hbuf, as_b, ad_b, N);
    hipLaunchKernelGGL((agg_kernel<true>), dim3(ngrid4), dim3(256), 0, stream,
                       (const unsigned*)hbuf, as_b, ad_b, rowstart, colv, b1, out, N);

    // --- layer 2 ---
    hipLaunchKernelGGL((proj_kernel<64>), dim3(pgrid), dim3(256), 0, stream,
                       out, W2, aS2, aD2, hbuf, as_b, ad_b, N);
    hipLaunchKernelGGL((agg_kernel<false>), dim3(ngrid4), dim3(256), 0, stream,
                       (const unsigned*)hbuf, as_b, ad_b, rowstart, colv, b2, out, N);
}

// Round 14
// 178.358 us; speedup vs baseline: 1.1984x; 1.0438x over previous
//
#include <hip/hip_runtime.h>
#include <hip/hip_bf16.h>

#define LRELU(x) ((x) > 0.f ? (x) : 0.2f * (x))
#define SCAN_TILE 1024
#define BSH 8          // bucket = 256 consecutive dst nodes (requires N < 131072)
#define EPB 4096       // edges per block in bucket phases

__device__ inline float bf_lo(unsigned w) { return __uint_as_float(w << 16); }
__device__ inline float bf_hi(unsigned w) { return __uint_as_float(w & 0xffff0000u); }
__device__ inline unsigned short f2bf(float f) {   // round-to-nearest-even bf16
    unsigned u = __float_as_uint(f);
    unsigned r = u + 0x7fffu + ((u >> 16) & 1u);
    return (unsigned short)(r >> 16);
}

// ---------------- Bucketed CSR build ----------------

__global__ void bucket_hist_kernel(const int* __restrict__ dst, int* __restrict__ bhist,
                                   int E, int NB) {
    __shared__ int cnt[256];
    int t = threadIdx.x;
    cnt[t] = 0;
    __syncthreads();
    int e0 = blockIdx.x * EPB + t;
#pragma unroll
    for (int i = 0; i < EPB / 256; ++i) {
        int e = e0 + i * 256;
        if (e < E) atomicAdd(&cnt[dst[e] >> BSH], 1);
    }
    __syncthreads();
    if (t < NB && cnt[t]) atomicAdd(&bhist[t], cnt[t]);
}

__global__ void bucket_scan_kernel(const int* __restrict__ bhist, int* __restrict__ boff,
                                   int* __restrict__ bcur, int NB) {
    int t = threadIdx.x;
    int v = (t < NB) ? bhist[t] : 0;
    int lane = t & 63, wid = t >> 6;
    int x = v;
#pragma unroll
    for (int off = 1; off < 64; off <<= 1) {
        int y = __shfl_up(x, off, 64);
        if (lane >= off) x += y;
    }
    __shared__ int sw[4], sw2[4];
    if (lane == 63) sw[wid] = x;
    __syncthreads();
    if (t == 0) { int a = 0; for (int w = 0; w < 4; ++w) { sw2[w] = a; a += sw[w]; } }
    __syncthreads();
    int excl = x - v + sw2[wid];
    if (t < NB) { boff[t] = excl; bcur[t] = excl; }
    if (t == NB - 1) boff[NB] = excl + v;   // == E
}

__global__ void bucket_scatter_kernel(const int* __restrict__ src, const int* __restrict__ dst,
                                      int* __restrict__ bcur, unsigned* __restrict__ ebuf, int E) {
    __shared__ int cnt[256];
    __shared__ int base[256];
    int t = threadIdx.x;
    cnt[t] = 0;
    __syncthreads();
    unsigned pk[EPB / 256];
    int bb[EPB / 256];
    int e0 = blockIdx.x * EPB + t;
#pragma unroll
    for (int i = 0; i < EPB / 256; ++i) {
        int e = e0 + i * 256;
        int b = -1; unsigned p = 0;
        if (e < E) {
            int s = src[e], d = dst[e];
            b = d >> BSH;
            p = (unsigned)s | ((unsigned)(d & ((1 << BSH) - 1)) << 17);
            atomicAdd(&cnt[b], 1);
        }
        bb[i] = b; pk[i] = p;
    }
    __syncthreads();
    if (cnt[t]) base[t] = atomicAdd(&bcur[t], cnt[t]);
    __syncthreads();
    cnt[t] = 0;
    __syncthreads();
#pragma unroll
    for (int i = 0; i < EPB / 256; ++i) {
        if (bb[i] >= 0) {
            int pos = base[bb[i]] + atomicAdd(&cnt[bb[i]], 1);
            ebuf[pos] = pk[i];
        }
    }
}

__global__ void deg_count_kernel(const unsigned* __restrict__ ebuf, const int* __restrict__ boff,
                                 int* __restrict__ deg, int n) {
    __shared__ int cnt[256];
    int t = threadIdx.x, b = blockIdx.x;
    cnt[t] = 0;
    __syncthreads();
    int beg = boff[b], end = boff[b + 1];
    for (int j = beg + t; j < end; j += 256)
        atomicAdd(&cnt[(ebuf[j] >> 17) & 255], 1);
    __syncthreads();
    int node = (b << BSH) + t;
    if (node < n) deg[node] = cnt[t];
}

__global__ void blocksum_kernel(const int* __restrict__ deg, int* __restrict__ bsum, int n) {
    int t = threadIdx.x;
    int i0 = blockIdx.x * SCAN_TILE + t * 4;
    int v = 0;
    if (i0 + 3 < n) {
        int4 q = *reinterpret_cast<const int4*>(deg + i0);
        v = q.x + q.y + q.z + q.w;
    } else {
#pragma unroll
        for (int k = 0; k < 4; ++k) if (i0 + k < n) v += deg[i0 + k];
    }
#pragma unroll
    for (int off = 32; off; off >>= 1) v += __shfl_xor(v, off, 64);
    __shared__ int sw[4];
    int lane = t & 63, wid = t >> 6;
    if (lane == 0) sw[wid] = v;
    __syncthreads();
    if (t == 0) bsum[blockIdx.x] = sw[0] + sw[1] + sw[2] + sw[3];
}

__global__ void scan_bsum_kernel(const int* __restrict__ bsum, int* __restrict__ boff,
                                 int* __restrict__ total_out, int nb) {
    int t = threadIdx.x;  // 1024 threads
    int v = (t < nb) ? bsum[t] : 0;
    int lane = t & 63, wid = t >> 6;
    int x = v;
#pragma unroll
    for (int off = 1; off < 64; off <<= 1) {
        int y = __shfl_up(x, off, 64);
        if (lane >= off) x += y;
    }
    __shared__ int sw[16], sw2[16];
    if (lane == 63) sw[wid] = x;
    __syncthreads();
    if (t == 0) {
        int a = 0;
#pragma unroll
        for (int w = 0; w < 16; ++w) { sw2[w] = a; a += sw[w]; }
    }
    __syncthreads();
    int incl = x + sw2[wid];
    if (t < nb) boff[t] = incl - v;
    if (t == nb - 1) *total_out = incl;
}

__global__ void scan_final_kernel(const int* __restrict__ deg, const int* __restrict__ boff,
                                  int* __restrict__ rowstart, int n) {
    int t = threadIdx.x;
    int i0 = blockIdx.x * SCAN_TILE + t * 4;
    int v0 = 0, v1 = 0, v2 = 0, v3 = 0;
    if (i0 + 3 < n) {
        int4 q = *reinterpret_cast<const int4*>(deg + i0);
        v0 = q.x; v1 = q.y; v2 = q.z; v3 = q.w;
    } else {
        if (i0     < n) v0 = deg[i0];
        if (i0 + 1 < n) v1 = deg[i0 + 1];
        if (i0 + 2 < n) v2 = deg[i0 + 2];
        if (i0 + 3 < n) v3 = deg[i0 + 3];
    }
    int tsum = v0 + v1 + v2 + v3;
    int lane = t & 63, wid = t >> 6;
    int x = tsum;
#pragma unroll
    for (int off = 1; off < 64; off <<= 1) {
        int y = __shfl_up(x, off, 64);
        if (lane >= off) x += y;
    }
    __shared__ int sw[4], sw2[4];
    if (lane == 63) sw[wid] = x;
    __syncthreads();
    if (t == 0) {
        int a = 0;
#pragma unroll
        for (int w = 0; w < 4; ++w) { sw2[w] = a; a += sw[w]; }
    }
    __syncthreads();
    int excl = x - tsum + sw2[wid] + boff[blockIdx.x];
    int e0 = excl, e1 = e0 + v0, e2 = e1 + v1, e3 = e2 + v2;
    if (i0     < n) rowstart[i0]     = e0;
    if (i0 + 1 < n) rowstart[i0 + 1] = e1;
    if (i0 + 2 < n) rowstart[i0 + 2] = e2;
    if (i0 + 3 < n) rowstart[i0 + 3] = e3;
}

__global__ void final_scatter_kernel(const unsigned* __restrict__ ebuf, const int* __restrict__ boff,
                                     const int* __restrict__ rowstart, int* __restrict__ colv, int n) {
    __shared__ int cur[256];
    int t = threadIdx.x, b = blockIdx.x;
    int node = (b << BSH) + t;
    if (node < n) cur[t] = rowstart[node];
    __syncthreads();
    int beg = boff[b], end = boff[b + 1];
    for (int j = beg + t; j < end; j += 256) {
        unsigned p = ebuf[j];
        int dlow = (p >> 17) & 255;
        int s = (int)(p & 0x1FFFF);
        int pos = atomicAdd(&cur[dlow], 1);
        colv[pos] = s;
    }
}

// ---------------- Projection: h(bf16) = x @ W (+ fused logits) ----------------
// W packed bf16x2 in LDS (16.6 KB vs 33 KB fp32) -> 6 blocks/CU (was 3): the kernel
// was LDS-read-latency bound at 22% occupancy; doubling resident waves hides it.

template <int K>
__global__ __launch_bounds__(256, 6) void proj_kernel(
        const float* __restrict__ x, const float* __restrict__ W,
        const float* __restrict__ a_src, const float* __restrict__ a_dst,
        __hip_bfloat16* __restrict__ h, float* __restrict__ as_out,
        float* __restrict__ ad_out, int n) {
    __shared__ unsigned Wtp[64 * (K / 2 + 1)];   // [col][kk] bf16x2, stride K/2+1
    __shared__ float xsh[16 * K];                // 16-row chunk (fp32)

    for (int i = threadIdx.x; i < (K / 2) * 64; i += 256) {
        int kk = i >> 6, c = i & 63;            // coalesced W reads
        unsigned short lo = f2bf(W[(2 * kk) * 64 + c]);
        unsigned short hi = f2bf(W[(2 * kk + 1) * 64 + c]);
        Wtp[c * (K / 2 + 1) + kk] = (unsigned)lo | ((unsigned)hi << 16);
    }

    int lane = threadIdx.x & 63, wid = threadIdx.x >> 6;
    float as_l = a_src[lane], ad_l = a_dst[lane];
    const float4* x4 = reinterpret_cast<const float4*>(x);
    float4* xsh4 = reinterpret_cast<float4*>(xsh);
    const int K4 = K / 4;
    int nchunk = (n + 15) >> 4;

    for (int ci = blockIdx.x; ci < nchunk; ci += gridDim.x) {
        int base = ci * 16;
        __syncthreads();
        for (int j = threadIdx.x; j < 16 * K4; j += 256) {
            int row = j / K4;
            int r = base + row;
            float4 v = make_float4(0.f, 0.f, 0.f, 0.f);
            if (r < n) v = x4[(size_t)r * K4 + (j - row * K4)];
            xsh4[j] = v;
        }
        __syncthreads();

        int r0 = base + wid * 4;
        float acc0 = 0.f, acc1 = 0.f, acc2 = 0.f, acc3 = 0.f;
        const unsigned* wl = Wtp + lane * (K / 2 + 1);
#pragma unroll 4
        for (int k4 = 0; k4 < K4; ++k4) {
            float4 va = xsh4[(wid * 4 + 0) * K4 + k4];
            float4 vb = xsh4[(wid * 4 + 1) * K4 + k4];
            float4 vc = xsh4[(wid * 4 + 2) * K4 + k4];
            float4 vd = xsh4[(wid * 4 + 3) * K4 + k4];
            unsigned wp0 = wl[2 * k4], wp1 = wl[2 * k4 + 1];
            float w0 = bf_lo(wp0), w1 = bf_hi(wp0);
            float w2 = bf_lo(wp1), w3 = bf_hi(wp1);
            acc0 = fmaf(va.x, w0, acc0); acc0 = fmaf(va.y, w1, acc0);
            acc0 = fmaf(va.z, w2, acc0); acc0 = fmaf(va.w, w3, acc0);
            acc1 = fmaf(vb.x, w0, acc1); acc1 = fmaf(vb.y, w1, acc1);
            acc1 = fmaf(vb.z, w2, acc1); acc1 = fmaf(vb.w, w3, acc1);
            acc2 = fmaf(vc.x, w0, acc2); acc2 = fmaf(vc.y, w1, acc2);
            acc2 = fmaf(vc.z, w2, acc2); acc2 = fmaf(vc.w, w3, acc2);
            acc3 = fmaf(vd.x, w0, acc3); acc3 = fmaf(vd.y, w1, acc3);
            acc3 = fmaf(vd.z, w2, acc3); acc3 = fmaf(vd.w, w3, acc3);
        }
        if (r0 + 0 < n) h[(size_t)(r0 + 0) * 64 + lane] = __float2bfloat16(acc0);
        if (r0 + 1 < n) h[(size_t)(r0 + 1) * 64 + lane] = __float2bfloat16(acc1);
        if (r0 + 2 < n) h[(size_t)(r0 + 2) * 64 + lane] = __float2bfloat16(acc2);
        if (r0 + 3 < n) h[(size_t)(r0 + 3) * 64 + lane] = __float2bfloat16(acc3);
        float s0 = acc0 * as_l, d0 = acc0 * ad_l;
        float s1 = acc1 * as_l, d1 = acc1 * ad_l;
        float s2 = acc2 * as_l, d2 = acc2 * ad_l;
        float s3 = acc3 * as_l, d3 = acc3 * ad_l;
#pragma unroll
        for (int off = 32; off; off >>= 1) {
            s0 += __shfl_xor(s0, off, 64); d0 += __shfl_xor(d0, off, 64);
            s1 += __shfl_xor(s1, off, 64); d1 += __shfl_xor(d1, off, 64);
            s2 += __shfl_xor(s2, off, 64); d2 += __shfl_xor(d2, off, 64);
            s3 += __shfl_xor(s3, off, 64); d3 += __shfl_xor(d3, off, 64);
        }
        if (lane == 0) {
            if (r0 + 0 < n) { as_out[r0 + 0] = s0; ad_out[r0 + 0] = d0; }
            if (r0 + 1 < n) { as_out[r0 + 1] = s1; ad_out[r0 + 1] = d1; }
            if (r0 + 2 < n) { as_out[r0 + 2] = s2; ad_out[r0 + 2] = d2; }
            if (r0 + 3 < n) { as_out[r0 + 3] = s3; ad_out[r0 + 3] = d3; }
        }
    }
}

// ---------------- Core half-wave agg loop (shared by both agg kernels) ----------------
// Returns denom + packed-feature-pair accumulator; lane = half*32 + fl.

template <typename F>
__device__ inline void agg_core(const unsigned* __restrict__ h32, const float* __restrict__ as_in,
                                float ad_n, int node, int beg, int end, int half, int fl,
                                const int* __restrict__ colv, float& denom, float2& acc) {
    denom = 0.f;
    acc = make_float2(0.f, 0.f);
    if (half == 0) {    // self-loop
        float ex = __expf(LRELU(as_in[node] + ad_n));
        unsigned hw = h32[(unsigned)node * 32u + fl];
        denom = ex;
        acc.x = bf_lo(hw) * ex;
        acc.y = bf_hi(hw) * ex;
    }
#define PAIR_STEP(sA, sB)                                             \
    {                                                                 \
        int s_ = half ? (sB) : (sA);                                  \
        bool valid_ = s_ >= 0;                                        \
        int ss_ = valid_ ? s_ : node;                                 \
        float a_ = as_in[ss_];                                        \
        unsigned hw_ = h32[(unsigned)ss_ * 32u + fl];                 \
        float xw_ = valid_ ? __expf(LRELU(a_ + ad_n)) : 0.f;          \
        denom += xw_;                                                 \
        acc.x = fmaf(bf_lo(hw_), xw_, acc.x);                         \
        acc.y = fmaf(bf_hi(hw_), xw_, acc.y);                         \
    }
    int i = beg;
    int pre = (beg + 3) & ~3;
    if (pre > end) pre = end;
    while (i < pre) {
        int sA = colv[i];
        bool two = (i + 1 < pre);
        int sB = two ? colv[i + 1] : -1;
        PAIR_STEP(sA, sB);
        i += two ? 2 : 1;
    }
    for (; i + 7 < end; i += 8) {
        int4 cA = *reinterpret_cast<const int4*>(colv + i);
        int4 cB = *reinterpret_cast<const int4*>(colv + i + 4);
        int s0 = half ? cA.y : cA.x;
        int s1 = half ? cA.w : cA.z;
        int s2 = half ? cB.y : cB.x;
        int s3 = half ? cB.w : cB.z;
        float a0 = as_in[s0], a1 = as_in[s1], a2 = as_in[s2], a3 = as_in[s3];
        unsigned w0 = h32[(unsigned)s0 * 32u + fl];
        unsigned w1 = h32[(unsigned)s1 * 32u + fl];
        unsigned w2 = h32[(unsigned)s2 * 32u + fl];
        unsigned w3 = h32[(unsigned)s3 * 32u + fl];
        float x0 = __expf(LRELU(a0 + ad_n));
        float x1 = __expf(LRELU(a1 + ad_n));
        float x2 = __expf(LRELU(a2 + ad_n));
        float x3 = __expf(LRELU(a3 + ad_n));
        denom += (x0 + x1) + (x2 + x3);
        acc.x = fmaf(bf_lo(w0), x0, acc.x); acc.y = fmaf(bf_hi(w0), x0, acc.y);
        acc.x = fmaf(bf_lo(w1), x1, acc.x); acc.y = fmaf(bf_hi(w1), x1, acc.y);
        acc.x = fmaf(bf_lo(w2), x2, acc.x); acc.y = fmaf(bf_hi(w2), x2, acc.y);
        acc.x = fmaf(bf_lo(w3), x3, acc.x); acc.y = fmaf(bf_hi(w3), x3, acc.y);
    }
    for (; i + 3 < end; i += 4) {
        int4 cA = *reinterpret_cast<const int4*>(colv + i);
        int s0 = half ? cA.y : cA.x;
        int s1 = half ? cA.w : cA.z;
        float a0 = as_in[s0], a1 = as_in[s1];
        unsigned w0 = h32[(unsigned)s0 * 32u + fl];
        unsigned w1 = h32[(unsigned)s1 * 32u + fl];
        float x0 = __expf(LRELU(a0 + ad_n));
        float x1 = __expf(LRELU(a1 + ad_n));
        denom += x0 + x1;
        acc.x = fmaf(bf_lo(w0), x0, acc.x); acc.y = fmaf(bf_hi(w0), x0, acc.y);
        acc.x = fmaf(bf_lo(w1), x1, acc.x); acc.y = fmaf(bf_hi(w1), x1, acc.y);
    }
    while (i < end) {
        int sA = colv[i];
        bool two = (i + 1 < end);
        int sB = two ? colv[i + 1] : -1;
        PAIR_STEP(sA, sB);
        i += two ? 2 : 1;
    }
#undef PAIR_STEP
    denom += __shfl_xor(denom, 32, 64);
    acc.x += __shfl_xor(acc.x, 32, 64);
    acc.y += __shfl_xor(acc.y, 32, 64);
}

// ---------------- agg1 + fused proj2: z1 never leaves the CU ----------------
// After computing z1 = elu(agg + b1) (half0 lanes hold 2 features each), the wave
// stages z1 in LDS and does h2[col=lane] = z1 . W2[:,lane] from bf16-packed LDS W2,
// then as2/ad2 wave-reductions. Eliminates the proj2 kernel and z1's global round-trip.

__global__ void agg_fuse_kernel(const unsigned* __restrict__ h32, const float* __restrict__ as_in,
                                const float* __restrict__ ad_in, const int* __restrict__ rowstart,
                                const int* __restrict__ colv, const float* __restrict__ bias,
                                const float* __restrict__ W2, const float* __restrict__ aS2,
                                const float* __restrict__ aD2,
                                unsigned short* __restrict__ h2out, float* __restrict__ as2_out,
                                float* __restrict__ ad2_out, int n) {
    __shared__ unsigned W2p[32 * 64];   // [kk][col] bf16x2 (k-pairs), 8 KB
    __shared__ float z1sh[4 * 64];      // per-wave z1 row

    for (int i = threadIdx.x; i < 32 * 64; i += 256) {
        int kk = i >> 6, c = i & 63;    // coalesced W2 reads
        unsigned short lo = f2bf(W2[(2 * kk) * 64 + c]);
        unsigned short hi = f2bf(W2[(2 * kk + 1) * 64 + c]);
        W2p[i] = (unsigned)lo | ((unsigned)hi << 16);
    }
    __syncthreads();

    int node = blockIdx.x * 4 + (int)(threadIdx.x >> 6);
    int lane = threadIdx.x & 63;
    if (node >= n) return;
    int half = lane >> 5, fl = lane & 31, wwid = threadIdx.x >> 6;

    float ad_n = ad_in[node];
    int beg = rowstart[node], end = rowstart[node + 1];
    float denom; float2 acc;
    agg_core<int>(h32, as_in, ad_n, node, beg, end, half, fl, colv, denom, acc);

    if (half == 0) {
        float2 bv = *reinterpret_cast<const float2*>(bias + 2 * fl);
        float ox = acc.x / denom + bv.x;
        float oy = acc.y / denom + bv.y;
        ox = ox > 0.f ? ox : __expf(ox) - 1.f;   // ELU
        oy = oy > 0.f ? oy : __expf(oy) - 1.f;
        *reinterpret_cast<float2*>(&z1sh[wwid * 64 + 2 * fl]) = make_float2(ox, oy);
    }
    // fused 64x64 GEMM: h2[col=lane] = sum_k z1[k] * W2[k][lane]
    float h2 = 0.f;
    const float* zrow = z1sh + wwid * 64;
#pragma unroll 8
    for (int kk = 0; kk < 32; ++kk) {
        float2 z = *reinterpret_cast<const float2*>(zrow + 2 * kk);  // wave-uniform broadcast
        unsigned wv = W2p[kk * 64 + lane];
        h2 = fmaf(z.x, bf_lo(wv), h2);
        h2 = fmaf(z.y, bf_hi(wv), h2);
    }
    h2out[(size_t)node * 64 + lane] = f2bf(h2);
    float s = h2 * aS2[lane], d = h2 * aD2[lane];
#pragma unroll
    for (int off = 32; off; off >>= 1) {
        s += __shfl_xor(s, off, 64);
        d += __shfl_xor(d, off, 64);
    }
    if (lane == 0) { as2_out[node] = s; ad2_out[node] = d; }
}

// ---------------- agg2: standard half-wave agg, writes final output ----------------

__global__ void agg_kernel(const unsigned* __restrict__ h32, const float* __restrict__ as_in,
                           const float* __restrict__ ad_in, const int* __restrict__ rowstart,
                           const int* __restrict__ colv, const float* __restrict__ bias,
                           float* __restrict__ out, int n) {
    int node = blockIdx.x * 4 + (int)(threadIdx.x >> 6);
    int lane = threadIdx.x & 63;
    if (node >= n) return;
    int half = lane >> 5, fl = lane & 31;

    float ad_n = ad_in[node];
    int beg = rowstart[node], end = rowstart[node + 1];
    float denom; float2 acc;
    agg_core<int>(h32, as_in, ad_n, node, beg, end, half, fl, colv, denom, acc);

    if (half == 0) {
        float2 bv = *reinterpret_cast<const float2*>(bias + 2 * fl);
        float ox = acc.x / denom + bv.x;
        float oy = acc.y / denom + bv.y;
        *reinterpret_cast<float2*>(out + (size_t)node * 64 + 2 * fl) = make_float2(ox, oy);
    }
}

// ---------------- Launch ----------------

extern "C" void kernel_launch(void* const* d_in, const int* in_sizes, int n_in,
                              void* d_out, int out_size, void* d_ws, size_t ws_size,
                              hipStream_t stream) {
    const float* x    = (const float*)d_in[0];
    const int*   eidx = (const int*)d_in[1];   // [2, E] flat
    const float* W1   = (const float*)d_in[2];
    const float* aS1  = (const float*)d_in[3];
    const float* aD1  = (const float*)d_in[4];
    const float* b1   = (const float*)d_in[5];
    const float* W2   = (const float*)d_in[6];
    const float* aS2  = (const float*)d_in[7];
    const float* aD2  = (const float*)d_in[8];
    const float* b2   = (const float*)d_in[9];
    float* out = (float*)d_out;

    const int F = 128, H = 64;
    const int N = in_sizes[0] / F;
    const int E = in_sizes[1] / 2;
    const int* src = eidx;
    const int* dst = eidx + E;

    // workspace carve-up
    char* p = (char*)d_ws;
    __hip_bfloat16* hbuf = (__hip_bfloat16*)p;  p += (size_t)N * H * sizeof(__hip_bfloat16);
    unsigned short* h2b  = (unsigned short*)p;  p += (size_t)N * H * sizeof(unsigned short);
    float* as_b  = (float*)p;             p += (size_t)N * sizeof(float);
    float* ad_b  = (float*)p;             p += (size_t)N * sizeof(float);
    float* as2_b = (float*)p;             p += (size_t)N * sizeof(float);
    float* ad2_b = (float*)p;             p += (size_t)N * sizeof(float);
    int* deg      = (int*)p;              p += (size_t)N * sizeof(int);
    int* rowstart = (int*)p;              p += (size_t)(N + 1) * sizeof(int);
    int* colv     = (int*)p;              p += (size_t)E * sizeof(int);
    int nb = (N + SCAN_TILE - 1) / SCAN_TILE;
    int* bsum   = (int*)p;                p += (size_t)nb * sizeof(int);
    int* bsoff  = (int*)p;                p += (size_t)nb * sizeof(int);
    int NB = (N + (1 << BSH) - 1) >> BSH;           // buckets (<= 256)
    int* bhist  = (int*)p;                p += (size_t)NB * sizeof(int);
    int* boff   = (int*)p;                p += (size_t)(NB + 1) * sizeof(int);
    int* bcur   = (int*)p;                p += (size_t)NB * sizeof(int);
    // ebuf aliases hbuf (E*4 B <= N*H*2 B): CSR build fully precedes proj1's h writes.
    unsigned* ebuf = (unsigned*)hbuf;

    int ngrid4 = (N + 3) / 4;
    int nbE = (E + EPB - 1) / EPB;
    int nchunk = (N + 15) / 16;
    int pgrid = nchunk < 1536 ? nchunk : 1536;   // 6 blocks/CU persistent

    // --- bucketed CSR build ---
    hipMemsetAsync(bhist, 0, (size_t)NB * sizeof(int), stream);
    hipLaunchKernelGGL(bucket_hist_kernel, dim3(nbE), dim3(256), 0, stream, dst, bhist, E, NB);
    hipLaunchKernelGGL(bucket_scan_kernel, dim3(1), dim3(256), 0, stream, bhist, boff, bcur, NB);
    hipLaunchKernelGGL(bucket_scatter_kernel, dim3(nbE), dim3(256), 0, stream, src, dst, bcur, ebuf, E);
    hipLaunchKernelGGL(deg_count_kernel, dim3(NB), dim3(256), 0, stream, ebuf, boff, deg, N);
    hipLaunchKernelGGL(blocksum_kernel, dim3(nb), dim3(256), 0, stream, deg, bsum, N);
    hipLaunchKernelGGL(scan_bsum_kernel, dim3(1), dim3(1024), 0, stream, bsum, bsoff, rowstart + N, nb);
    hipLaunchKernelGGL(scan_final_kernel, dim3(nb), dim3(256), 0, stream, deg, bsoff, rowstart, N);
    hipLaunchKernelGGL(final_scatter_kernel, dim3(NB), dim3(256), 0, stream, ebuf, boff, rowstart, colv, N);

    // --- layer 1 (proj) ---
    hipLaunchKernelGGL((proj_kernel<128>), dim3(pgrid), dim3(256), 0, stream,
                       x, W1, aS1, aD1, hbuf, as_b, ad_b, N);
    // --- layer 1 agg + fused layer 2 proj/logits ---
    hipLaunchKernelGGL(agg_fuse_kernel, dim3(ngrid4), dim3(256), 0, stream,
                       (const unsigned*)hbuf, as_b, ad_b, rowstart, colv, b1,
                       W2, aS2, aD2, h2b, as2_b, ad2_b, N);
    // --- layer 2 agg ---
    hipLaunchKernelGGL(agg_kernel, dim3(ngrid4), dim3(256), 0, stream,
                       (const unsigned*)h2b, as2_b, ad2_b, rowstart, colv, b2, out, N);
}

// Round 17
// 169.485 us; speedup vs baseline: 1.2611x; 1.0523x over previous
//
#include <hip/hip_runtime.h>
#include <hip/hip_bf16.h>

#define LRELU(x) ((x) > 0.f ? (x) : 0.2f * (x))
#define LOG2E 1.44269504088896340736f
#define EXP2F(x) __builtin_amdgcn_exp2f(x)
#define BSH 8          // bucket = 256 consecutive dst nodes (requires N < 131072)
#define EPB 4096       // edges per block in bucket phases

__device__ inline float bf_lo(unsigned w) { return __uint_as_float(w << 16); }
__device__ inline float bf_hi(unsigned w) { return __uint_as_float(w & 0xffff0000u); }
__device__ inline unsigned short f2bf(float f) {   // round-to-nearest-even bf16
    unsigned u = __float_as_uint(f);
    unsigned r = u + 0x7fffu + ((u >> 16) & 1u);
    return (unsigned short)(r >> 16);
}

// ---------------- Bucketed CSR build (5 launches total) ----------------
// Edge packing: bits [0,17) = src, bits [17,25) = dst & 255; bucket implicit in slab.

__global__ void bucket_hist_kernel(const int* __restrict__ dst, int* __restrict__ bhist,
                                   int E, int NB) {
    __shared__ int cnt[256];
    int t = threadIdx.x;
    cnt[t] = 0;
    __syncthreads();
    int e0 = blockIdx.x * EPB + t;
#pragma unroll
    for (int i = 0; i < EPB / 256; ++i) {
        int e = e0 + i * 256;
        if (e < E) atomicAdd(&cnt[dst[e] >> BSH], 1);
    }
    __syncthreads();
    if (t < NB && cnt[t]) atomicAdd(&bhist[t], cnt[t]);
}

__global__ void bucket_scan_kernel(const int* __restrict__ bhist, int* __restrict__ boff,
                                   int* __restrict__ bcur, int NB) {
    int t = threadIdx.x;
    int v = (t < NB) ? bhist[t] : 0;
    int lane = t & 63, wid = t >> 6;
    int x = v;
#pragma unroll
    for (int off = 1; off < 64; off <<= 1) {
        int y = __shfl_up(x, off, 64);
        if (lane >= off) x += y;
    }
    __shared__ int sw[4], sw2[4];
    if (lane == 63) sw[wid] = x;
    __syncthreads();
    if (t == 0) { int a = 0; for (int w = 0; w < 4; ++w) { sw2[w] = a; a += sw[w]; } }
    __syncthreads();
    int excl = x - v + sw2[wid];
    if (t < NB) { boff[t] = excl; bcur[t] = excl; }
    if (t == NB - 1) boff[NB] = excl + v;   // == E
}

__global__ void bucket_scatter_kernel(const int* __restrict__ src, const int* __restrict__ dst,
                                      int* __restrict__ bcur, unsigned* __restrict__ ebuf, int E) {
    __shared__ int cnt[256];
    __shared__ int base[256];
    int t = threadIdx.x;
    cnt[t] = 0;
    __syncthreads();
    unsigned pk[EPB / 256];
    int bb[EPB / 256];
    int e0 = blockIdx.x * EPB + t;
#pragma unroll
    for (int i = 0; i < EPB / 256; ++i) {
        int e = e0 + i * 256;
        int b = -1; unsigned p = 0;
        if (e < E) {
            int s = src[e], d = dst[e];
            b = d >> BSH;
            p = (unsigned)s | ((unsigned)(d & ((1 << BSH) - 1)) << 17);
            atomicAdd(&cnt[b], 1);
        }
        bb[i] = b; pk[i] = p;
    }
    __syncthreads();
    if (cnt[t]) base[t] = atomicAdd(&bcur[t], cnt[t]);
    __syncthreads();
    cnt[t] = 0;
    __syncthreads();
#pragma unroll
    for (int i = 0; i < EPB / 256; ++i) {
        if (bb[i] >= 0) {
            int pos = base[bb[i]] + atomicAdd(&cnt[bb[i]], 1);
            ebuf[pos] = pk[i];
        }
    }
}

// One block per bucket: count per-node degrees, in-block exclusive scan
// (rowstart[node] = boff[b] + excl), then scatter colv with LDS cursors.
// Replaces deg_count + 3-phase scan + final_scatter.
__global__ void build_csr_kernel(const unsigned* __restrict__ ebuf, const int* __restrict__ boff,
                                 int* __restrict__ rowstart, int* __restrict__ colv,
                                 int n, int E) {
    __shared__ int cnt[256];
    __shared__ int sw[4], sw2[4];
    int t = threadIdx.x, b = blockIdx.x;
    cnt[t] = 0;
    __syncthreads();
    int beg = boff[b], end = boff[b + 1];
    for (int j = beg + t; j < end; j += 256)
        atomicAdd(&cnt[(ebuf[j] >> 17) & 255], 1);
    __syncthreads();
    int v = cnt[t];
    int lane = t & 63, wid = t >> 6;
    int x = v;
#pragma unroll
    for (int off = 1; off < 64; off <<= 1) {
        int y = __shfl_up(x, off, 64);
        if (lane >= off) x += y;
    }
    if (lane == 63) sw[wid] = x;
    __syncthreads();
    if (t == 0) { int a = 0; for (int w = 0; w < 4; ++w) { sw2[w] = a; a += sw[w]; } }
    __syncthreads();
    int excl = x - v + sw2[wid] + beg;
    int node = (b << BSH) + t;
    if (node < n) rowstart[node] = excl;
    if (node == n - 1) rowstart[n] = E;
    __syncthreads();
    cnt[t] = excl;      // reuse as cursor
    __syncthreads();
    for (int j = beg + t; j < end; j += 256) {
        unsigned p = ebuf[j];
        int dlow = (p >> 17) & 255;
        int s = (int)(p & 0x1FFFF);
        int pos = atomicAdd(&cnt[dlow], 1);
        colv[pos] = s;
    }
}

// ---------------- proj1: h(bf16) = x @ W1 (+ fused logits, pre-scaled by log2e) --------

template <int K>
__global__ __launch_bounds__(256, 6) void proj_kernel(
        const float* __restrict__ x, const float* __restrict__ W,
        const float* __restrict__ a_src, const float* __restrict__ a_dst,
        __hip_bfloat16* __restrict__ h, float* __restrict__ as_out,
        float* __restrict__ ad_out, int n) {
    __shared__ unsigned Wtp[64 * (K / 2 + 1)];   // [col][kk] bf16x2, stride K/2+1
    __shared__ float xsh[16 * K];                // 16-row chunk (fp32)

    for (int i = threadIdx.x; i < (K / 2) * 64; i += 256) {
        int kk = i >> 6, c = i & 63;            // coalesced W reads
        unsigned short lo = f2bf(W[(2 * kk) * 64 + c]);
        unsigned short hi = f2bf(W[(2 * kk + 1) * 64 + c]);
        Wtp[c * (K / 2 + 1) + kk] = (unsigned)lo | ((unsigned)hi << 16);
    }

    int lane = threadIdx.x & 63, wid = threadIdx.x >> 6;
    float as_l = a_src[lane] * LOG2E, ad_l = a_dst[lane] * LOG2E;  // exp2 trick
    const float4* x4 = reinterpret_cast<const float4*>(x);
    float4* xsh4 = reinterpret_cast<float4*>(xsh);
    const int K4 = K / 4;
    int nchunk = (n + 15) >> 4;

    for (int ci = blockIdx.x; ci < nchunk; ci += gridDim.x) {
        int base = ci * 16;
        __syncthreads();
        for (int j = threadIdx.x; j < 16 * K4; j += 256) {
            int row = j / K4;
            int r = base + row;
            float4 v = make_float4(0.f, 0.f, 0.f, 0.f);
            if (r < n) v = x4[(size_t)r * K4 + (j - row * K4)];
            xsh4[j] = v;
        }
        __syncthreads();

        int r0 = base + wid * 4;
        float acc0 = 0.f, acc1 = 0.f, acc2 = 0.f, acc3 = 0.f;
        const unsigned* wl = Wtp + lane * (K / 2 + 1);
#pragma unroll 4
        for (int k4 = 0; k4 < K4; ++k4) {
            float4 va = xsh4[(wid * 4 + 0) * K4 + k4];
            float4 vb = xsh4[(wid * 4 + 1) * K4 + k4];
            float4 vc = xsh4[(wid * 4 + 2) * K4 + k4];
            float4 vd = xsh4[(wid * 4 + 3) * K4 + k4];
            unsigned wp0 = wl[2 * k4], wp1 = wl[2 * k4 + 1];
            float w0 = bf_lo(wp0), w1 = bf_hi(wp0);
            float w2 = bf_lo(wp1), w3 = bf_hi(wp1);
            acc0 = fmaf(va.x, w0, acc0); acc0 = fmaf(va.y, w1, acc0);
            acc0 = fmaf(va.z, w2, acc0); acc0 = fmaf(va.w, w3, acc0);
            acc1 = fmaf(vb.x, w0, acc1); acc1 = fmaf(vb.y, w1, acc1);
            acc1 = fmaf(vb.z, w2, acc1); acc1 = fmaf(vb.w, w3, acc1);
            acc2 = fmaf(vc.x, w0, acc2); acc2 = fmaf(vc.y, w1, acc2);
            acc2 = fmaf(vc.z, w2, acc2); acc2 = fmaf(vc.w, w3, acc2);
            acc3 = fmaf(vd.x, w0, acc3); acc3 = fmaf(vd.y, w1, acc3);
            acc3 = fmaf(vd.z, w2, acc3); acc3 = fmaf(vd.w, w3, acc3);
        }
        if (r0 + 0 < n) h[(size_t)(r0 + 0) * 64 + lane] = __float2bfloat16(acc0);
        if (r0 + 1 < n) h[(size_t)(r0 + 1) * 64 + lane] = __float2bfloat16(acc1);
        if (r0 + 2 < n) h[(size_t)(r0 + 2) * 64 + lane] = __float2bfloat16(acc2);
        if (r0 + 3 < n) h[(size_t)(r0 + 3) * 64 + lane] = __float2bfloat16(acc3);
        float s0 = acc0 * as_l, d0 = acc0 * ad_l;
        float s1 = acc1 * as_l, d1 = acc1 * ad_l;
        float s2 = acc2 * as_l, d2 = acc2 * ad_l;
        float s3 = acc3 * as_l, d3 = acc3 * ad_l;
#pragma unroll
        for (int off = 32; off; off >>= 1) {
            s0 += __shfl_xor(s0, off, 64); d0 += __shfl_xor(d0, off, 64);
            s1 += __shfl_xor(s1, off, 64); d1 += __shfl_xor(d1, off, 64);
            s2 += __shfl_xor(s2, off, 64); d2 += __shfl_xor(d2, off, 64);
            s3 += __shfl_xor(s3, off, 64); d3 += __shfl_xor(d3, off, 64);
        }
        if (lane == 0) {
            if (r0 + 0 < n) { as_out[r0 + 0] = s0; ad_out[r0 + 0] = d0; }
            if (r0 + 1 < n) { as_out[r0 + 1] = s1; ad_out[r0 + 1] = d1; }
            if (r0 + 2 < n) { as_out[r0 + 2] = s2; ad_out[r0 + 2] = d2; }
            if (r0 + 3 < n) { as_out[r0 + 3] = s3; ad_out[r0 + 3] = d3; }
        }
    }
}

// ---------------- proj2: h2(bf16) = z1(packed bf16) @ W2 (+ fused logits) ----------------
// Dedicated row-blocked GEMM (4 accumulators share every W/z read) -- ~4x fewer
// issue-slots/row than the R14 in-agg fused GEMM.

__global__ __launch_bounds__(256, 6) void proj2_kernel(
        const unsigned* __restrict__ z1p, const float* __restrict__ W,
        const float* __restrict__ a_src, const float* __restrict__ a_dst,
        __hip_bfloat16* __restrict__ h, float* __restrict__ as_out,
        float* __restrict__ ad_out, int n) {
    const int K = 64;
    __shared__ unsigned Wtp[64 * 33];   // [col][kk] bf16x2, stride 33 (conflict-free)
    __shared__ float xsh[16 * K];       // 16-row z1 chunk, unpacked to fp32

    for (int i = threadIdx.x; i < 32 * 64; i += 256) {
        int kk = i >> 6, c = i & 63;
        unsigned short lo = f2bf(W[(2 * kk) * 64 + c]);
        unsigned short hi = f2bf(W[(2 * kk + 1) * 64 + c]);
        Wtp[c * 33 + kk] = (unsigned)lo | ((unsigned)hi << 16);
    }

    int lane = threadIdx.x & 63, wid = threadIdx.x >> 6;
    float as_l = a_src[lane] * LOG2E, ad_l = a_dst[lane] * LOG2E;
    float4* xsh4 = reinterpret_cast<float4*>(xsh);
    const int K4 = K / 4;
    int nchunk = (n + 15) >> 4;

    for (int ci = blockIdx.x; ci < nchunk; ci += gridDim.x) {
        int base = ci * 16;
        __syncthreads();
        // stage 16 rows of packed z1 (u32 = 2 bf16), unpack to fp32
        for (int j = threadIdx.x; j < 16 * 32; j += 256) {
            int row = j >> 5, c2 = j & 31;
            int r = base + row;
            unsigned pv = (r < n) ? z1p[(size_t)r * 32 + c2] : 0u;
            xsh[row * K + 2 * c2]     = bf_lo(pv);
            xsh[row * K + 2 * c2 + 1] = bf_hi(pv);
        }
        __syncthreads();

        int r0 = base + wid * 4;
        float acc0 = 0.f, acc1 = 0.f, acc2 = 0.f, acc3 = 0.f;
        const unsigned* wl = Wtp + lane * 33;
#pragma unroll 4
        for (int k4 = 0; k4 < K4; ++k4) {
            float4 va = xsh4[(wid * 4 + 0) * K4 + k4];
            float4 vb = xsh4[(wid * 4 + 1) * K4 + k4];
            float4 vc = xsh4[(wid * 4 + 2) * K4 + k4];
            float4 vd = xsh4[(wid * 4 + 3) * K4 + k4];
            unsigned wp0 = wl[2 * k4], wp1 = wl[2 * k4 + 1];
            float w0 = bf_lo(wp0), w1 = bf_hi(wp0);
            float w2 = bf_lo(wp1), w3 = bf_hi(wp1);
            acc0 = fmaf(va.x, w0, acc0); acc0 = fmaf(va.y, w1, acc0);
            acc0 = fmaf(va.z, w2, acc0); acc0 = fmaf(va.w, w3, acc0);
            acc1 = fmaf(vb.x, w0, acc1); acc1 = fmaf(vb.y, w1, acc1);
            acc1 = fmaf(vb.z, w2, acc1); acc1 = fmaf(vb.w, w3, acc1);
            acc2 = fmaf(vc.x, w0, acc2); acc2 = fmaf(vc.y, w1, acc2);
            acc2 = fmaf(vc.z, w2, acc2); acc2 = fmaf(vc.w, w3, acc2);
            acc3 = fmaf(vd.x, w0, acc3); acc3 = fmaf(vd.y, w1, acc3);
            acc3 = fmaf(vd.z, w2, acc3); acc3 = fmaf(vd.w, w3, acc3);
        }
        if (r0 + 0 < n) h[(size_t)(r0 + 0) * 64 + lane] = __float2bfloat16(acc0);
        if (r0 + 1 < n) h[(size_t)(r0 + 1) * 64 + lane] = __float2bfloat16(acc1);
        if (r0 + 2 < n) h[(size_t)(r0 + 2) * 64 + lane] = __float2bfloat16(acc2);
        if (r0 + 3 < n) h[(size_t)(r0 + 3) * 64 + lane] = __float2bfloat16(acc3);
        float s0 = acc0 * as_l, d0 = acc0 * ad_l;
        float s1 = acc1 * as_l, d1 = acc1 * ad_l;
        float s2 = acc2 * as_l, d2 = acc2 * ad_l;
        float s3 = acc3 * as_l, d3 = acc3 * ad_l;
#pragma unroll
        for (int off = 32; off; off >>= 1) {
            s0 += __shfl_xor(s0, off, 64); d0 += __shfl_xor(d0, off, 64);
            s1 += __shfl_xor(s1, off, 64); d1 += __shfl_xor(d1, off, 64);
            s2 += __shfl_xor(s2, off, 64); d2 += __shfl_xor(d2, off, 64);
            s3 += __shfl_xor(s3, off, 64); d3 += __shfl_xor(d3, off, 64);
        }
        if (lane == 0) {
            if (r0 + 0 < n) { as_out[r0 + 0] = s0; ad_out[r0 + 0] = d0; }
            if (r0 + 1 < n) { as_out[r0 + 1] = s1; ad_out[r0 + 1] = d1; }
            if (r0 + 2 < n) { as_out[r0 + 2] = s2; ad_out[r0 + 2] = d2; }
            if (r0 + 3 < n) { as_out[r0 + 3] = s3; ad_out[r0 + 3] = d3; }
        }
    }
}

// ---------------- Core half-wave agg loop ----------------
// Logits are pre-scaled by log2e -> weights via exp2 (v_exp_f32 native; 1 fewer VALU/edge).

__device__ inline void agg_core(const unsigned* __restrict__ h32, const float* __restrict__ as_in,
                                float ad_n, int node, int beg, int end, int half, int fl,
                                const int* __restrict__ colv, float& denom, float2& acc) {
    denom = 0.f;
    acc = make_float2(0.f, 0.f);
    if (half == 0) {    // self-loop
        float ex = EXP2F(LRELU(as_in[node] + ad_n));
        unsigned hw = h32[(unsigned)node * 32u + fl];
        denom = ex;
        acc.x = bf_lo(hw) * ex;
        acc.y = bf_hi(hw) * ex;
    }
#define PAIR_STEP(sA, sB)                                             \
    {                                                                 \
        int s_ = half ? (sB) : (sA);                                  \
        bool valid_ = s_ >= 0;                                        \
        int ss_ = valid_ ? s_ : node;                                 \
        float a_ = as_in[ss_];                                        \
        unsigned hw_ = h32[(unsigned)ss_ * 32u + fl];                 \
        float xw_ = valid_ ? EXP2F(LRELU(a_ + ad_n)) : 0.f;           \
        denom += xw_;                                                 \
        acc.x = fmaf(bf_lo(hw_), xw_, acc.x);                         \
        acc.y = fmaf(bf_hi(hw_), xw_, acc.y);                         \
    }
    int i = beg;
    int pre = (beg + 3) & ~3;
    if (pre > end) pre = end;
    while (i < pre) {
        int sA = colv[i];
        bool two = (i + 1 < pre);
        int sB = two ? colv[i + 1] : -1;
        PAIR_STEP(sA, sB);
        i += two ? 2 : 1;
    }
    for (; i + 7 < end; i += 8) {
        int4 cA = *reinterpret_cast<const int4*>(colv + i);
        int4 cB = *reinterpret_cast<const int4*>(colv + i + 4);
        int s0 = half ? cA.y : cA.x;
        int s1 = half ? cA.w : cA.z;
        int s2 = half ? cB.y : cB.x;
        int s3 = half ? cB.w : cB.z;
        float a0 = as_in[s0], a1 = as_in[s1], a2 = as_in[s2], a3 = as_in[s3];
        unsigned w0 = h32[(unsigned)s0 * 32u + fl];
        unsigned w1 = h32[(unsigned)s1 * 32u + fl];
        unsigned w2 = h32[(unsigned)s2 * 32u + fl];
        unsigned w3 = h32[(unsigned)s3 * 32u + fl];
        float x0 = EXP2F(LRELU(a0 + ad_n));
        float x1 = EXP2F(LRELU(a1 + ad_n));
        float x2 = EXP2F(LRELU(a2 + ad_n));
        float x3 = EXP2F(LRELU(a3 + ad_n));
        denom += (x0 + x1) + (x2 + x3);
        acc.x = fmaf(bf_lo(w0), x0, acc.x); acc.y = fmaf(bf_hi(w0), x0, acc.y);
        acc.x = fmaf(bf_lo(w1), x1, acc.x); acc.y = fmaf(bf_hi(w1), x1, acc.y);
        acc.x = fmaf(bf_lo(w2), x2, acc.x); acc.y = fmaf(bf_hi(w2), x2, acc.y);
        acc.x = fmaf(bf_lo(w3), x3, acc.x); acc.y = fmaf(bf_hi(w3), x3, acc.y);
    }
    for (; i + 3 < end; i += 4) {
        int4 cA = *reinterpret_cast<const int4*>(colv + i);
        int s0 = half ? cA.y : cA.x;
        int s1 = half ? cA.w : cA.z;
        float a0 = as_in[s0], a1 = as_in[s1];
        unsigned w0 = h32[(unsigned)s0 * 32u + fl];
        unsigned w1 = h32[(unsigned)s1 * 32u + fl];
        float x0 = EXP2F(LRELU(a0 + ad_n));
        float x1 = EXP2F(LRELU(a1 + ad_n));
        denom += x0 + x1;
        acc.x = fmaf(bf_lo(w0), x0, acc.x); acc.y = fmaf(bf_hi(w0), x0, acc.y);
        acc.x = fmaf(bf_lo(w1), x1, acc.x); acc.y = fmaf(bf_hi(w1), x1, acc.y);
    }
    while (i < end) {
        int sA = colv[i];
        bool two = (i + 1 < end);
        int sB = two ? colv[i + 1] : -1;
        PAIR_STEP(sA, sB);
        i += two ? 2 : 1;
    }
#undef PAIR_STEP
    denom += __shfl_xor(denom, 32, 64);
    acc.x += __shfl_xor(acc.x, 32, 64);
    acc.y += __shfl_xor(acc.y, 32, 64);
}

// ---------------- agg1: softmax-agg + bias + ELU -> packed bf16 z1 ----------------

__global__ void agg1_kernel(const unsigned* __restrict__ h32, const float* __restrict__ as_in,
                            const float* __restrict__ ad_in, const int* __restrict__ rowstart,
                            const int* __restrict__ colv, const float* __restrict__ bias,
                            unsigned* __restrict__ z1p, int n) {
    int node = blockIdx.x * 4 + (int)(threadIdx.x >> 6);
    int lane = threadIdx.x & 63;
    if (node >= n) return;
    int half = lane >> 5, fl = lane & 31;

    float ad_n = ad_in[node];
    int beg = rowstart[node], end = rowstart[node + 1];
    float denom; float2 acc;
    agg_core(h32, as_in, ad_n, node, beg, end, half, fl, colv, denom, acc);

    if (half == 0) {
        float2 bv = *reinterpret_cast<const float2*>(bias + 2 * fl);
        float ox = acc.x / denom + bv.x;
        float oy = acc.y / denom + bv.y;
        ox = ox > 0.f ? ox : __expf(ox) - 1.f;   // ELU
        oy = oy > 0.f ? oy : __expf(oy) - 1.f;
        z1p[(size_t)node * 32 + fl] = (unsigned)f2bf(ox) | ((unsigned)f2bf(oy) << 16);
    }
}

// ---------------- agg2: softmax-agg + bias -> final fp32 output ----------------

__global__ void agg2_kernel(const unsigned* __restrict__ h32, const float* __restrict__ as_in,
                            const float* __restrict__ ad_in, const int* __restrict__ rowstart,
                            const int* __restrict__ colv, const float* __restrict__ bias,
                            float* __restrict__ out, int n) {
    int node = blockIdx.x * 4 + (int)(threadIdx.x >> 6);
    int lane = threadIdx.x & 63;
    if (node >= n) return;
    int half = lane >> 5, fl = lane & 31;

    float ad_n = ad_in[node];
    int beg = rowstart[node], end = rowstart[node + 1];
    float denom; float2 acc;
    agg_core(h32, as_in, ad_n, node, beg, end, half, fl, colv, denom, acc);

    if (half == 0) {
        float2 bv = *reinterpret_cast<const float2*>(bias + 2 * fl);
        float ox = acc.x / denom + bv.x;
        float oy = acc.y / denom + bv.y;
        *reinterpret_cast<float2*>(out + (size_t)node * 64 + 2 * fl) = make_float2(ox, oy);
    }
}

// ---------------- Launch ----------------

extern "C" void kernel_launch(void* const* d_in, const int* in_sizes, int n_in,
                              void* d_out, int out_size, void* d_ws, size_t ws_size,
                              hipStream_t stream) {
    const float* x    = (const float*)d_in[0];
    const int*   eidx = (const int*)d_in[1];   // [2, E] flat
    const float* W1   = (const float*)d_in[2];
    const float* aS1  = (const float*)d_in[3];
    const float* aD1  = (const float*)d_in[4];
    const float* b1   = (const float*)d_in[5];
    const float* W2   = (const float*)d_in[6];
    const float* aS2  = (const float*)d_in[7];
    const float* aD2  = (const float*)d_in[8];
    const float* b2   = (const float*)d_in[9];
    float* out = (float*)d_out;

    const int F = 128, H = 64;
    const int N = in_sizes[0] / F;
    const int E = in_sizes[1] / 2;
    const int* src = eidx;
    const int* dst = eidx + E;

    // workspace carve-up
    char* p = (char*)d_ws;
    __hip_bfloat16* hbuf = (__hip_bfloat16*)p;  p += (size_t)N * H * sizeof(__hip_bfloat16);
    __hip_bfloat16* h2b  = (__hip_bfloat16*)p;  p += (size_t)N * H * sizeof(__hip_bfloat16);
    unsigned* z1p = (unsigned*)p;         p += (size_t)N * (H / 2) * sizeof(unsigned);
    float* as_b  = (float*)p;             p += (size_t)N * sizeof(float);
    float* ad_b  = (float*)p;             p += (size_t)N * sizeof(float);
    float* as2_b = (float*)p;             p += (size_t)N * sizeof(float);
    float* ad2_b = (float*)p;             p += (size_t)N * sizeof(float);
    int* rowstart = (int*)p;              p += (size_t)(N + 1) * sizeof(int);
    int* colv     = (int*)p;              p += (size_t)E * sizeof(int);
    int NB = (N + (1 << BSH) - 1) >> BSH;           // buckets (<= 256)
    int* bhist  = (int*)p;                p += (size_t)NB * sizeof(int);
    int* boff   = (int*)p;                p += (size_t)(NB + 1) * sizeof(int);
    int* bcur   = (int*)p;                p += (size_t)NB * sizeof(int);
    // ebuf aliases hbuf (E*4 B <= N*H*2 B): CSR build fully precedes proj1's h writes.
    unsigned* ebuf = (unsigned*)hbuf;

    int ngrid4 = (N + 3) / 4;
    int nbE = (E + EPB - 1) / EPB;
    int nchunk = (N + 15) / 16;
    int pgrid = nchunk < 1536 ? nchunk : 1536;   // persistent, 6 blocks/CU

    // --- bucketed CSR build (5 launches) ---
    (void)hipMemsetAsync(bhist, 0, (size_t)NB * sizeof(int), stream);
    hipLaunchKernelGGL(bucket_hist_kernel, dim3(nbE), dim3(256), 0, stream, dst, bhist, E, NB);
    hipLaunchKernelGGL(bucket_scan_kernel, dim3(1), dim3(256), 0, stream, bhist, boff, bcur, NB);
    hipLaunchKernelGGL(bucket_scatter_kernel, dim3(nbE), dim3(256), 0, stream, src, dst, bcur, ebuf, E);
    hipLaunchKernelGGL(build_csr_kernel, dim3(NB), dim3(256), 0, stream, ebuf, boff, rowstart, colv, N, E);

    // --- layer 1 ---
    hipLaunchKernelGGL((proj_kernel<128>), dim3(pgrid), dim3(256), 0, stream,
                       x, W1, aS1, aD1, hbuf, as_b, ad_b, N);
    hipLaunchKernelGGL(agg1_kernel, dim3(ngrid4), dim3(256), 0, stream,
                       (const unsigned*)hbuf, as_b, ad_b, rowstart, colv, b1, z1p, N);

    // --- layer 2 ---
    hipLaunchKernelGGL(proj2_kernel, dim3(pgrid), dim3(256), 0, stream,
                       z1p, W2, aS2, aD2, h2b, as2_b, ad2_b, N);
    hipLaunchKernelGGL(agg2_kernel, dim3(ngrid4), dim3(256), 0, stream,
                       (const unsigned*)h2b, as2_b, ad2_b, rowstart, colv, b2, out, N);
}